// Round 7
// baseline (870.784 us; speedup 1.0000x reference)
//
#include <hip/hip_runtime.h>
#include <cstdint>

// ---------------- problem constants ----------------
constexpr int B_ = 2, S_ = 1024, D_ = 1024, DS_ = 320, NSLOT_ = 512;
constexpr int H_ = 4, CH_ = 5, DFF_ = 4096;
constexpr int HD_ = D_ / H_;      // 256
constexpr int CHD_ = DS_ / CH_;   // 64
constexpr int BS_ = B_ * S_;      // 2048
constexpr int BNS_ = B_ * NSLOT_; // 1024

typedef unsigned short u16;
typedef __attribute__((ext_vector_type(8))) short bf16x8;
typedef __attribute__((ext_vector_type(4))) float f32x4;
typedef __attribute__((ext_vector_type(4))) u16 u16x4;

__device__ __forceinline__ u16 f2bf(float f) {
  unsigned u = __float_as_uint(f);
  return (u16)((u + 0x7FFFu + ((u >> 16) & 1u)) >> 16);  // RNE
}
__device__ __forceinline__ float bf2f(u16 h) { return __uint_as_float((unsigned)h << 16); }

__device__ __forceinline__ void gload16(const void* g, void* l) {
  __builtin_amdgcn_global_load_lds((const __attribute__((address_space(1))) void*)g,
                                   (__attribute__((address_space(3))) void*)l, 16, 0, 0);
}

// ---------------- bf16 MFMA GEMM: C[m,n] = sum_k A[m,k]*B[n,k] ----------------
// BM=128, BK=64, 512 threads (8 waves). Fully unrolled over NSTEPS (template):
// buffer parity and all LDS/global offsets are compile-time -> ds_read uses
// one address VGPR + offset immediates; per-step VALU ~0 (r6 post-mortem:
// VALUBusy was 2x MfmaUtil from runtime address math).
//   BN=256: waves 2x4, per-wave 64x64 (2.0 MFMA/ds_read), LDS 96KB, lb(512,2)
//   BN=128: waves 4x2, per-wave 32x64
//   BN=64 : waves 8x1, per-wave 16x64
// Double-buffered, counted vmcnt (never 0 mid-loop). XOR-swizzle: linear
// gload_lds dest, source granule ^= row&7, same involution on reads
// (0 bank conflicts, verified r3/r6).
template<int BN, int NSTEPS>
__global__ __launch_bounds__(512, (BN == 256) ? 2 : 4)
void k_gemm(const u16* __restrict__ A, int lda, long long sA, long long sA2,
            const u16* __restrict__ Bp, int ldb, long long sB, long long sB2,
            float* __restrict__ outF, u16* __restrict__ outB,
            int ldc, long long sC, long long sC2,
            u16* __restrict__ outBT, int ldt, long long sT, long long sT2,
            int zdiv, const float* __restrict__ bias,
            const float* __restrict__ rowscale, int act)
{
  constexpr int BM = 128;
  constexpr int NB = BN / 64;               // B-tile gloads per stage
  constexpr int MI = (BN == 256) ? 4 : (BN == 128 ? 2 : 1);
  constexpr int NI = 4;
  constexpr int WROWS = MI * 16;
  constexpr int ABYT = BM * 128;            // 16 KB (128 rows x 128 B)
  constexpr int BBYT = BN * 128;
  constexpr int BUF = ABYT + BBYT;
  const int z = blockIdx.z, zb = z / zdiv, zr = z - zb * zdiv;
  A  += (long long)zb * sA + (long long)zr * sA2;
  Bp += (long long)zb * sB + (long long)zr * sB2;
  const long long cof = (long long)zb * sC + (long long)zr * sC2;
  const long long tof = (long long)zb * sT + (long long)zr * sT2;
  const int bm = blockIdx.y * BM, bn = blockIdx.x * BN;
  __shared__ __align__(16) char lds[2 * BUF];
  const int tid = threadIdx.x;
  const int lane = tid & 63, wid = tid >> 6;
  const int wm = (BN == 256) ? (wid >> 2) : (BN == 128 ? (wid >> 1) : wid);
  const int wn = (BN == 256) ? (wid & 3) : (BN == 128 ? (wid & 1) : 0);
  const int rowb = wm * WROWS, colb = wn * 64;

  f32x4 acc[MI][NI];
  const f32x4 fz = {0.f, 0.f, 0.f, 0.f};
  #pragma unroll
  for (int i = 0; i < MI; ++i)
    #pragma unroll
    for (int j = 0; j < NI; ++j) acc[i][j] = fz;

  // staging: thread t -> row t>>3 (64 rows per 512-thr pass), granule t&7;
  // source granule = (t&7) ^ (row&7); LDS dest linear (tid*16 within pass).
  const int trow = tid >> 3;
  const int tg   = ((tid & 7) ^ (trow & 7)) * 8;   // element offset in row
  const u16* gA  = A + (long long)(bm + trow) * lda + tg;
  const u16* gA2 = gA + (long long)64 * lda;
  const u16* gBr[NB];
  {
    const u16* g0 = Bp + (long long)(bn + trow) * ldb + tg;
    #pragma unroll
    for (int b = 0; b < NB; ++b) gBr[b] = g0 + (long long)(64 * b) * ldb;
  }

  // fragment read offsets: row' = base + i*16 + r; granule (4s+q) ^ (r&7)
  const int r = lane & 15, q = lane >> 4;
  const int c7 = r & 7;
  const int gs0 = ((q) ^ c7) << 4;
  const int gs1 = ((4 + q) ^ c7) << 4;
  int aoff[MI], boff[NI];
  #pragma unroll
  for (int i = 0; i < MI; ++i) aoff[i] = (rowb + i * 16 + r) * 128;
  #pragma unroll
  for (int j = 0; j < NI; ++j) boff[j] = (colb + j * 16 + r) * 128;

  auto stage = [&](int buf, int it) {
    char* la = lds + buf * BUF + wid * 1024;
    char* lb = la + ABYT;
    const int ko = it << 6;                  // element offset (it*64)
    gload16(gA + ko, la);
    gload16(gA2 + ko, la + 8192);
    #pragma unroll
    for (int b = 0; b < NB; ++b) gload16(gBr[b] + ko, lb + b * 8192);
  };

  stage(0, 0);
  #pragma unroll
  for (int it = 0; it < NSTEPS; ++it) {
    if (it + 1 < NSTEPS) {
      stage((it + 1) & 1, it + 1);
      if constexpr (BN == 256)      asm volatile("s_waitcnt vmcnt(6)" ::: "memory");
      else if constexpr (BN == 128) asm volatile("s_waitcnt vmcnt(4)" ::: "memory");
      else                          asm volatile("s_waitcnt vmcnt(3)" ::: "memory");
    } else {
      asm volatile("s_waitcnt vmcnt(0)" ::: "memory");
    }
    __builtin_amdgcn_s_barrier();           // buf[it&1] landed for all waves
    __builtin_amdgcn_sched_barrier(0);
    const char* pa = lds + (it & 1) * BUF;
    const char* pb = pa + ABYT;
    #pragma unroll
    for (int s = 0; s < 2; ++s) {
      const int gso = s ? gs1 : gs0;
      bf16x8 af[MI], bv[NI];
      #pragma unroll
      for (int i = 0; i < MI; ++i) af[i] = *(const bf16x8*)(pa + aoff[i] + gso);
      #pragma unroll
      for (int j = 0; j < NI; ++j) bv[j] = *(const bf16x8*)(pb + boff[j] + gso);
      #pragma unroll
      for (int i = 0; i < MI; ++i)
        #pragma unroll
        for (int j = 0; j < NI; ++j)
          acc[i][j] = __builtin_amdgcn_mfma_f32_16x16x32_bf16(af[i], bv[j], acc[i][j], 0, 0, 0);
    }
    asm volatile("s_waitcnt lgkmcnt(0)" ::: "memory");  // this wave's ds_reads done
    __builtin_amdgcn_sched_barrier(0);
    __builtin_amdgcn_s_barrier();           // safe to overwrite buf[it&1]
  }

  const int fr = lane & 15, fq = lane >> 4;
  #pragma unroll
  for (int i = 0; i < MI; ++i) {
    const int r0 = bm + rowb + i * 16 + fq * 4;
    #pragma unroll
    for (int j = 0; j < NI; ++j) {
      const int cn = bn + colb + j * 16 + fr;
      const float bvv = bias ? bias[cn] : 0.f;
      float vv[4];
      #pragma unroll
      for (int t = 0; t < 4; ++t) {
        float v = acc[i][j][t] + bvv;
        if (rowscale) v *= rowscale[r0 + t];
        if (act) v = 0.5f * v * (1.f + tanhf(0.7978845608028654f * (v + 0.044715f * v * v * v)));
        vv[t] = v;
      }
      if (outF) {
        #pragma unroll
        for (int t = 0; t < 4; ++t) outF[cof + (long long)(r0 + t) * ldc + cn] = vv[t];
      }
      if (outB) {
        #pragma unroll
        for (int t = 0; t < 4; ++t) outB[cof + (long long)(r0 + t) * ldc + cn] = f2bf(vv[t]);
      }
      if (outBT) {
        u16x4 pk = {f2bf(vv[0]), f2bf(vv[1]), f2bf(vv[2]), f2bf(vv[3])};
        *(u16x4*)(outBT + tof + (long long)cn * ldt + r0) = pk;
      }
    }
  }
}

// ---------------- transpose + convert: in[R][C] fp32 -> out[C][R] bf16 ----------------
__global__ __launch_bounds__(256)
void k_tcvt(const float* __restrict__ in, u16* __restrict__ out, int R, int C)
{
  __shared__ float t[32][33];
  const int bx = blockIdx.x * 32, by = blockIdx.y * 32;
  const int tx = threadIdx.x & 31, ty = threadIdx.x >> 5;
  #pragma unroll
  for (int i = 0; i < 32; i += 8)
    t[ty + i][tx] = in[(long long)(by + ty + i) * C + bx + tx];
  __syncthreads();
  #pragma unroll
  for (int i = 0; i < 32; i += 8)
    out[(long long)(bx + ty + i) * R + by + tx] = f2bf(t[tx][ty + i]);
}

// ---------------- convert fp32 -> bf16 ----------------
__global__ __launch_bounds__(256)
void k_cvt(const float* __restrict__ in, u16* __restrict__ out, int n)
{
  int i = blockIdx.x * 256 + threadIdx.x;
  if (i < n) out[i] = f2bf(in[i]);
}

// ---------------- row softmax on bf16 in place (cols <= 1024) ----------------
__global__ __launch_bounds__(256)
void k_softmax_b16(u16* __restrict__ x, int cols, float scale)
{
  u16* p = x + (long long)blockIdx.x * cols;
  const int tid = threadIdx.x;
  __shared__ float red[256];
  float v[4];
  float m = -1e30f;
  #pragma unroll
  for (int i = 0; i < 4; ++i) {
    const int c = tid + (i << 8);
    v[i] = (c < cols) ? bf2f(p[c]) * scale : -1e30f;
    m = fmaxf(m, v[i]);
  }
  red[tid] = m; __syncthreads();
  for (int s = 128; s > 0; s >>= 1) { if (tid < s) red[tid] = fmaxf(red[tid], red[tid + s]); __syncthreads(); }
  m = red[0]; __syncthreads();
  float sum = 0.f;
  #pragma unroll
  for (int i = 0; i < 4; ++i) { v[i] = expf(v[i] - m); sum += v[i]; }
  red[tid] = sum; __syncthreads();
  for (int s = 128; s > 0; s >>= 1) { if (tid < s) red[tid] += red[tid + s]; __syncthreads(); }
  const float inv = 1.f / red[0];
  #pragma unroll
  for (int i = 0; i < 4; ++i) {
    const int c = tid + (i << 8);
    if (c < cols) p[c] = f2bf(v[i] * inv);
  }
}

// ---------------- layernorm: LN(x [+res])*g + b -> fp32 out (opt) + bf16 out (opt) ----------------
__global__ __launch_bounds__(256)
void k_layernorm(const float* __restrict__ x, const float* __restrict__ res,
                 const float* __restrict__ g, const float* __restrict__ b,
                 float* __restrict__ outF, u16* __restrict__ outB, int cols)
{
  const long long ro = (long long)blockIdx.x * cols;
  const float* px = x + ro;
  const float* pr = res ? res + ro : nullptr;
  __shared__ float red[256];
  const int tid = threadIdx.x;
  float s = 0.f;
  for (int c = tid; c < cols; c += 256) { float v = px[c] + (pr ? pr[c] : 0.f); s += v; }
  red[tid] = s; __syncthreads();
  for (int t = 128; t > 0; t >>= 1) { if (tid < t) red[tid] += red[tid + t]; __syncthreads(); }
  const float mean = red[0] / cols; __syncthreads();
  float s2 = 0.f;
  for (int c = tid; c < cols; c += 256) { float v = px[c] + (pr ? pr[c] : 0.f) - mean; s2 += v * v; }
  red[tid] = s2; __syncthreads();
  for (int t = 128; t > 0; t >>= 1) { if (tid < t) red[tid] += red[tid + t]; __syncthreads(); }
  const float inv = rsqrtf(red[0] / cols + 1e-5f);
  for (int c = tid; c < cols; c += 256) {
    float v = (px[c] + (pr ? pr[c] : 0.f) - mean) * inv * g[c] + b[c];
    if (outF) outF[ro + c] = v;
    if (outB) outB[ro + c] = f2bf(v);
  }
}

// ---------------- gate[row] = sigmoid(dot(x[row], w) + b0), 1 wave / row ----------------
__global__ __launch_bounds__(256)
void k_gate(const float* __restrict__ x, const float* __restrict__ w,
            const float* __restrict__ b0, float* __restrict__ out, int cols)
{
  const int lane = threadIdx.x & 63;
  const int wv = threadIdx.x >> 6;
  const long long row = (long long)blockIdx.x * 4 + wv;
  const float* p = x + row * cols;
  float s = 0.f;
  for (int c = lane; c < cols; c += 64) s += p[c] * w[c];
  #pragma unroll
  for (int off = 32; off > 0; off >>= 1) s += __shfl_down(s, off);
  if (lane == 0) out[row] = 1.0f / (1.0f + expf(-(s + b0[0])));
}

// ---------------- elementwise ----------------
__global__ __launch_bounds__(256)
void k_combine2(float* __restrict__ oF, u16* __restrict__ oB,
                const float* __restrict__ a, float sa, const float* __restrict__ b,
                const float* __restrict__ emb, int n, int Dm1)
{
  int i = blockIdx.x * 256 + threadIdx.x;
  if (i >= n) return;
  float v = sa * a[i];
  if (b) v += b[i];
  v += emb[i & Dm1];
  oF[i] = v; oB[i] = f2bf(v);
}

__global__ __launch_bounds__(256)
void k_gated_add(float* __restrict__ out, const float* __restrict__ h,
                 const float* __restrict__ r, const float* __restrict__ gate, int n, int Dv)
{
  int i = blockIdx.x * 256 + threadIdx.x;
  if (i >= n) return;
  out[i] = h[i] + gate[i / Dv] * r[i];
}

__global__ __launch_bounds__(256)
void k_add2(float* __restrict__ oF, u16* __restrict__ oB,
            const float* __restrict__ a, const float* __restrict__ b, int n)
{
  int i = blockIdx.x * 256 + threadIdx.x;
  if (i >= n) return;
  float v = a[i] + b[i];
  oF[i] = v; oB[i] = f2bf(v);
}

// ---------------- host ----------------
extern "C" void kernel_launch(void* const* d_in, const int* in_sizes, int n_in,
                              void* d_out, int out_size, void* d_ws, size_t ws_size,
                              hipStream_t stream)
{
  (void)in_sizes; (void)n_in; (void)out_size;
  const float* x        = (const float*)d_in[0];
  const float* cache0   = (const float*)d_in[1];
  const float* iter_emb = (const float*)d_in[2];
  const float* rq_w     = (const float*)d_in[3];
  const float* rg_w     = (const float*)d_in[4];
  const float* rg_b     = (const float*)d_in[5];
  const float* ck_w     = (const float*)d_in[6];
  const float* cv_w     = (const float*)d_in[7];
  const float* aq_w     = (const float*)d_in[8];
  const float* ak_w     = (const float*)d_in[9];
  const float* av_w     = (const float*)d_in[10];
  const float* ao_w     = (const float*)d_in[11];
  const float* aq_b     = (const float*)d_in[12];
  const float* ak_b     = (const float*)d_in[13];
  const float* av_b     = (const float*)d_in[14];
  const float* ao_b     = (const float*)d_in[15];
  const float* f1_w     = (const float*)d_in[16];
  const float* f1_b     = (const float*)d_in[17];
  const float* f2_w     = (const float*)d_in[18];
  const float* f2_b     = (const float*)d_in[19];
  const float* n1_g     = (const float*)d_in[20];
  const float* n1_b     = (const float*)d_in[21];
  const float* n2_g     = (const float*)d_in[22];
  const float* n2_b     = (const float*)d_in[23];
  const float* sq_w     = (const float*)d_in[24];
  const float* tk_w     = (const float*)d_in[25];
  const float* tv_w     = (const float*)d_in[26];
  const float* wg_w     = (const float*)d_in[27];
  const float* wg_b     = (const float*)d_in[28];
  const float* cq_w     = (const float*)d_in[29];
  const float* ck2_w    = (const float*)d_in[30];
  const float* cv2_w    = (const float*)d_in[31];
  const float* co_w     = (const float*)d_in[32];
  const float* cq_b     = (const float*)d_in[33];
  const float* ck2_b    = (const float*)d_in[34];
  const float* cv2_b    = (const float*)d_in[35];
  const float* co_b     = (const float*)d_in[36];
  const float* cn_g     = (const float*)d_in[37];
  const float* cn_b     = (const float*)d_in[38];
  // d_in[39] = max_iterations (fixed 2; schedule hardcoded for graph capture)

  float* out = (float*)d_out;

  // -------- workspace carve --------
  size_t off = 0;
  char* base = (char*)d_ws;
  auto allocF = [&](size_t n) { float* p = (float*)(base + off); off += n * 4; off = (off + 255) & ~(size_t)255; return p; };
  auto allocH = [&](size_t n) { u16* p = (u16*)(base + off); off += n * 2; off = (off + 255) & ~(size_t)255; return p; };

  float* hbuf  = allocF((size_t)BS_ * D_);
  float* henh  = allocF((size_t)BS_ * D_);
  float* hcomp = allocF((size_t)BS_ * D_);
  float* h2b   = allocF((size_t)BS_ * D_);
  float* tA    = allocF((size_t)BS_ * D_);
  float* gate  = allocF((size_t)BS_);
  float* ccnf  = allocF((size_t)BNS_ * DS_);
  float* updf  = allocF((size_t)BNS_ * DS_);
  float* coo   = allocF((size_t)BNS_ * DS_);
  float* ccwf  = allocF((size_t)BNS_ * DS_);
  u16* rqT  = allocH((size_t)D_ * D_);
  u16* ckT  = allocH((size_t)D_ * DS_);
  u16* cvT  = allocH((size_t)D_ * DS_);
  u16* aqT  = allocH((size_t)D_ * D_);
  u16* akT  = allocH((size_t)D_ * D_);
  u16* avT  = allocH((size_t)D_ * D_);
  u16* aoT  = allocH((size_t)D_ * D_);
  u16* f1T  = allocH((size_t)DFF_ * D_);
  u16* f2T  = allocH((size_t)D_ * DFF_);
  u16* sqT  = allocH((size_t)DS_ * DS_);
  u16* tkT  = allocH((size_t)DS_ * D_);
  u16* tvTw = allocH((size_t)DS_ * D_);
  u16* cqT  = allocH((size_t)DS_ * DS_);
  u16* ck2T = allocH((size_t)DS_ * DS_);
  u16* cv2T = allocH((size_t)DS_ * DS_);
  u16* coT  = allocH((size_t)DS_ * DS_);
  u16* bb1  = allocH((size_t)BS_ * D_);
  u16* bb2  = allocH((size_t)BS_ * D_);
  u16* bb3  = allocH((size_t)BS_ * D_);
  u16* bb4  = allocH((size_t)BS_ * D_);
  u16* bb5  = allocH((size_t)B_ * H_ * S_ * S_);
  u16* cc0b = allocH((size_t)BNS_ * DS_);
  u16* ccwb = allocH((size_t)BNS_ * DS_);
  u16* sqb  = allocH((size_t)BNS_ * DS_);
  u16* tkb  = allocH((size_t)BS_ * DS_);
  u16* tvTb = allocH((size_t)DS_ * BS_);
  u16* ccnb = allocH((size_t)BNS_ * DS_);
  u16* cqb  = allocH((size_t)BNS_ * DS_);
  u16* ck2b = allocH((size_t)BNS_ * DS_);
  u16* cv2Tb= allocH((size_t)DS_ * BNS_);
  u16* csab = allocH((size_t)BNS_ * DS_);
  if (off > ws_size) return;

  auto gemm = [&](int M, int N, int K, int z, int zdiv,
                  const u16* Ap, int lda, long long sa, long long sa2,
                  const u16* Bq, int ldb, long long sb, long long sb2,
                  float* oF, u16* oB, int ldc, long long sc, long long sc2,
                  u16* oBT, int ldt, long long st, long long st2,
                  const float* bias, const float* rsc, int act) {
    const int ns = K >> 6;
#define GARGS Ap, lda, sa, sa2, Bq, ldb, sb, sb2, oF, oB, ldc, sc, sc2, oBT, ldt, st, st2, zdiv, bias, rsc, act
    if ((N % 256) == 0 && (long long)(N / 256) * (M / 128) * z >= 224) {
      dim3 g(N / 256, M / 128, z);
      if      (ns == 4)  k_gemm<256, 4><<<g, 512, 0, stream>>>(GARGS);
      else if (ns == 8)  k_gemm<256, 8><<<g, 512, 0, stream>>>(GARGS);
      else if (ns == 16) k_gemm<256, 16><<<g, 512, 0, stream>>>(GARGS);
      else { dim3 g2(N / 64, M / 128, z);
             if (ns == 64) k_gemm<64, 64><<<g2, 512, 0, stream>>>(GARGS); }
    } else {
      dim3 g(N / 64, M / 128, z);
      if      (ns == 1)  k_gemm<64, 1><<<g, 512, 0, stream>>>(GARGS);
      else if (ns == 4)  k_gemm<64, 4><<<g, 512, 0, stream>>>(GARGS);
      else if (ns == 5)  k_gemm<64, 5><<<g, 512, 0, stream>>>(GARGS);
      else if (ns == 8)  k_gemm<64, 8><<<g, 512, 0, stream>>>(GARGS);
      else if (ns == 16) k_gemm<64, 16><<<g, 512, 0, stream>>>(GARGS);
      else if (ns == 64) k_gemm<64, 64><<<g, 512, 0, stream>>>(GARGS);
    }
#undef GARGS
  };
  auto tcvt = [&](const float* in, u16* o, int R, int C) {
    dim3 g(C / 32, R / 32);
    k_tcvt<<<g, 256, 0, stream>>>(in, o, R, C);
  };
  auto lnorm = [&](const float* xp, const float* rp, const float* g, const float* b,
                   float* oF, u16* oB, int rows, int cols) {
    k_layernorm<<<rows, 256, 0, stream>>>(xp, rp, g, b, oF, oB, cols);
  };
  auto eg = [](int n) { return dim3((n + 255) / 256); };

  // ---- weight prep ----
  tcvt(rq_w, rqT, D_, D_);
  tcvt(ck_w, ckT, DS_, D_);
  tcvt(cv_w, cvT, DS_, D_);
  tcvt(aq_w, aqT, D_, D_);
  tcvt(ak_w, akT, D_, D_);
  tcvt(av_w, avT, D_, D_);
  tcvt(ao_w, aoT, D_, D_);
  tcvt(f1_w, f1T, D_, DFF_);
  tcvt(f2_w, f2T, DFF_, D_);
  tcvt(sq_w, sqT, DS_, DS_);
  tcvt(tk_w, tkT, D_, DS_);
  tcvt(tv_w, tvTw, D_, DS_);
  tcvt(cq_w, cqT, DS_, DS_);
  tcvt(ck2_w, ck2T, DS_, DS_);
  tcvt(cv2_w, cv2T, DS_, DS_);
  tcvt(co_w, coT, DS_, DS_);
  k_cvt<<<eg(BNS_ * DS_), 256, 0, stream>>>(cache0, cc0b, BNS_ * DS_);

  // ---- mem_read ----
  auto mem_read = [&](const float* h_f, const u16* h_b, const u16* cc_b, float* o_henh) {
    gemm(BS_, D_, D_, 1, 1, h_b, D_, 0, 0, rqT, D_, 0, 0,
         nullptr, bb2, D_, 0, 0, nullptr, 0, 0, 0, nullptr, nullptr, 0);            // q
    gemm(BNS_, D_, DS_, 1, 1, cc_b, DS_, 0, 0, ckT, DS_, 0, 0,
         nullptr, bb3, D_, 0, 0, nullptr, 0, 0, 0, nullptr, nullptr, 0);            // k
    gemm(BNS_, D_, DS_, 1, 1, cc_b, DS_, 0, 0, cvT, DS_, 0, 0,
         nullptr, nullptr, 0, 0, 0, bb4, BNS_, 0, 0, nullptr, nullptr, 0);          // v^T
    gemm(S_, NSLOT_, D_, B_, 1, bb2, D_, (long long)S_ * D_, 0,
         bb3, D_, (long long)NSLOT_ * D_, 0,
         nullptr, bb5, NSLOT_, (long long)S_ * NSLOT_, 0,
         nullptr, 0, 0, 0, nullptr, nullptr, 0);                                    // q k^T
    k_softmax_b16<<<B_ * S_, 256, 0, stream>>>(bb5, NSLOT_, 0.03125f);
    gemm(S_, D_, NSLOT_, B_, 1, bb5, NSLOT_, (long long)S_ * NSLOT_, 0,
         bb4, BNS_, NSLOT_, 0,
         tA, nullptr, D_, (long long)S_ * D_, 0,
         nullptr, 0, 0, 0, nullptr, nullptr, 0);                                    // readout
    k_gate<<<BS_ / 4, 256, 0, stream>>>(h_f, rg_w, rg_b, gate, D_);
    k_gated_add<<<eg(BS_ * D_), 256, 0, stream>>>(o_henh, h_f, tA, gate, BS_ * D_, D_);
  };

  // ---- compute_block ----
  auto compute_block = [&](const float* he, float* oF, u16* oB) {
    lnorm(he, nullptr, n1_g, n1_b, nullptr, bb1, BS_, D_);
    gemm(BS_, D_, D_, 1, 1, bb1, D_, 0, 0, aqT, D_, 0, 0,
         nullptr, bb2, D_, 0, 0, nullptr, 0, 0, 0, aq_b, nullptr, 0);               // qa
    gemm(BS_, D_, D_, 1, 1, bb1, D_, 0, 0, akT, D_, 0, 0,
         nullptr, bb3, D_, 0, 0, nullptr, 0, 0, 0, ak_b, nullptr, 0);               // ka
    gemm(BS_, D_, D_, 1, 1, bb1, D_, 0, 0, avT, D_, 0, 0,
         nullptr, nullptr, 0, 0, 0, bb4, BS_, 0, 0, av_b, nullptr, 0);              // va^T
    gemm(S_, S_, HD_, B_ * H_, H_,
         bb2, D_, (long long)S_ * D_, HD_,
         bb3, D_, (long long)S_ * D_, HD_,
         nullptr, bb5, S_, (long long)H_ * S_ * S_, (long long)S_ * S_,
         nullptr, 0, 0, 0, nullptr, nullptr, 0);                                    // scores (BN=256 path)
    k_softmax_b16<<<B_ * H_ * S_, 256, 0, stream>>>(bb5, S_, 0.0625f);
    gemm(S_, HD_, S_, B_ * H_, H_,
         bb5, S_, (long long)H_ * S_ * S_, (long long)S_ * S_,
         bb4, BS_, S_, (long long)HD_ * BS_,
         nullptr, bb2, D_, (long long)S_ * D_, HD_,
         nullptr, 0, 0, 0, nullptr, nullptr, 0);                                    // attnv
    gemm(BS_, D_, D_, 1, 1, bb2, D_, 0, 0, aoT, D_, 0, 0,
         tA, nullptr, D_, 0, 0, nullptr, 0, 0, 0, ao_b, nullptr, 0);                // attno
    lnorm(he, tA, n1_g, n1_b, h2b, bb1, BS_, D_);
    gemm(BS_, DFF_, D_, 1, 1, bb1, D_, 0, 0, f1T, D_, 0, 0,
         nullptr, bb5, DFF_, 0, 0, nullptr, 0, 0, 0, f1_b, nullptr, 1);             // f1+gelu (BN=256)
    gemm(BS_, D_, DFF_, 1, 1, bb5, DFF_, 0, 0, f2T, DFF_, 0, 0,
         tA, nullptr, D_, 0, 0, nullptr, 0, 0, 0, f2_b, nullptr, 0);                // f2
    lnorm(h2b, tA, n2_g, n2_b, oF, oB, BS_, D_);
  };

  // ---- mem_write + cache self-attn (skipped in last iter) ----
  auto mem_write_csa = [&](const float* hc_f, const u16* hc_b,
                           const float* ccin_f, const u16* ccin_b) {
    gemm(BNS_, DS_, DS_, 1, 1, ccin_b, DS_, 0, 0, sqT, DS_, 0, 0,
         nullptr, sqb, DS_, 0, 0, nullptr, 0, 0, 0, nullptr, nullptr, 0);           // sq
    gemm(BS_, DS_, D_, 1, 1, hc_b, D_, 0, 0, tkT, D_, 0, 0,
         nullptr, tkb, DS_, 0, 0, nullptr, 0, 0, 0, nullptr, nullptr, 0);           // tk
    k_gate<<<BS_ / 4, 256, 0, stream>>>(hc_f, wg_w, wg_b, gate, D_);
    gemm(BS_, DS_, D_, 1, 1, hc_b, D_, 0, 0, tvTw, D_, 0, 0,
         nullptr, nullptr, 0, 0, 0, tvTb, BS_, 0, 0, nullptr, gate, 0);             // (gate*tv)^T
    gemm(NSLOT_, S_, DS_, B_, 1, sqb, DS_, (long long)NSLOT_ * DS_, 0,
         tkb, DS_, (long long)S_ * DS_, 0,
         nullptr, bb5, S_, (long long)NSLOT_ * S_, 0,
         nullptr, 0, 0, 0, nullptr, nullptr, 0);                                    // slot scores
    k_softmax_b16<<<B_ * NSLOT_, 256, 0, stream>>>(bb5, S_, 0.05590169943749474f);
    gemm(NSLOT_, DS_, S_, B_, 1, bb5, S_, (long long)NSLOT_ * S_, 0,
         tvTb, BS_, S_, 0,
         updf, nullptr, DS_, (long long)NSLOT_ * DS_, 0,
         nullptr, 0, 0, 0, nullptr, nullptr, 0);                                    // upd
    k_add2<<<eg(BNS_ * DS_), 256, 0, stream>>>(ccnf, ccnb, ccin_f, updf, BNS_ * DS_);
    gemm(BNS_, DS_, DS_, 1, 1, ccnb, DS_, 0, 0, cqT, DS_, 0, 0,
         nullptr, cqb, DS_, 0, 0, nullptr, 0, 0, 0, cq_b, nullptr, 0);              // cq
    gemm(BNS_, DS_, DS_, 1, 1, ccnb, DS_, 0, 0, ck2T, DS_, 0, 0,
         nullptr, ck2b, DS_, 0, 0, nullptr, 0, 0, 0, ck2_b, nullptr, 0);            // ck
    gemm(BNS_, DS_, DS_, 1, 1, ccnb, DS_, 0, 0, cv2T, DS_, 0, 0,
         nullptr, nullptr, 0, 0, 0, cv2Tb, BNS_, 0, 0, cv2_b, nullptr, 0);          // cv^T
    gemm(NSLOT_, NSLOT_, CHD_, B_ * CH_, CH_,
         cqb, DS_, (long long)NSLOT_ * DS_, CHD_,
         ck2b, DS_, (long long)NSLOT_ * DS_, CHD_,
         nullptr, bb5, NSLOT_, (long long)CH_ * NSLOT_ * NSLOT_, (long long)NSLOT_ * NSLOT_,
         nullptr, 0, 0, 0, nullptr, nullptr, 0);                                    // csa scores
    k_softmax_b16<<<B_ * CH_ * NSLOT_, 256, 0, stream>>>(bb5, NSLOT_, 0.125f);
    gemm(NSLOT_, CHD_, NSLOT_, B_ * CH_, CH_,
         bb5, NSLOT_, (long long)CH_ * NSLOT_ * NSLOT_, (long long)NSLOT_ * NSLOT_,
         cv2Tb, BNS_, NSLOT_, (long long)CHD_ * BNS_,
         nullptr, csab, DS_, (long long)NSLOT_ * DS_, CHD_,
         nullptr, 0, 0, 0, nullptr, nullptr, 0);                                    // csa pv
    gemm(BNS_, DS_, DS_, 1, 1, csab, DS_, 0, 0, coT, DS_, 0, 0,
         coo, nullptr, DS_, 0, 0, nullptr, 0, 0, 0, co_b, nullptr, 0);              // co
    lnorm(ccnf, coo, cn_g, cn_b, ccwf, ccwb, BNS_, DS_);
  };

  // ================= iteration 0 =================
  k_combine2<<<eg(BS_ * D_), 256, 0, stream>>>(hbuf, bb1, x, 1.0f, nullptr, iter_emb, BS_ * D_, D_ - 1);
  mem_read(hbuf, bb1, cc0b, henh);
  compute_block(henh, hcomp, bb3);
  mem_write_csa(hcomp, bb3, cache0, cc0b);

  // ================= iteration 1 (last: cache update dead, skipped) =================
  k_combine2<<<eg(BS_ * D_), 256, 0, stream>>>(hbuf, bb1, hcomp, 2.0f, x, iter_emb + D_, BS_ * D_, D_ - 1);
  mem_read(hbuf, bb1, ccwb, henh);
  compute_block(henh, out, nullptr);
}

// Round 8
// 740.510 us; speedup vs baseline: 1.1759x; 1.1759x over previous
//
#include <hip/hip_runtime.h>
#include <cstdint>

// ---------------- problem constants ----------------
constexpr int B_ = 2, S_ = 1024, D_ = 1024, DS_ = 320, NSLOT_ = 512;
constexpr int H_ = 4, CH_ = 5, DFF_ = 4096;
constexpr int HD_ = D_ / H_;      // 256
constexpr int CHD_ = DS_ / CH_;   // 64
constexpr int BS_ = B_ * S_;      // 2048
constexpr int BNS_ = B_ * NSLOT_; // 1024

typedef unsigned short u16;
typedef __attribute__((ext_vector_type(8))) short bf16x8;
typedef __attribute__((ext_vector_type(4))) float f32x4;
typedef __attribute__((ext_vector_type(4))) u16 u16x4;

__device__ __forceinline__ u16 f2bf(float f) {
  unsigned u = __float_as_uint(f);
  return (u16)((u + 0x7FFFu + ((u >> 16) & 1u)) >> 16);  // RNE
}
__device__ __forceinline__ float bf2f(u16 h) { return __uint_as_float((unsigned)h << 16); }

__device__ __forceinline__ void gload16(const void* g, void* l) {
  __builtin_amdgcn_global_load_lds((const __attribute__((address_space(1))) void*)g,
                                   (__attribute__((address_space(3))) void*)l, 16, 0, 0);
}

// ---------------- bf16 MFMA GEMM: C[m,n] = sum_k A[m,k]*B[n,k] ----------------
// Round-6 geometry (proven 45us/MfmaUtil 14.6): BM=128, BK=64, 512 thr.
//   BN=128: waves 4x2, per-wave 32x64, LDS 2x32KB=64KB  (2 blocks/CU)
//   BN=64 : waves 8x1, per-wave 16x64, LDS 2x24KB=48KB  (3 blocks/CU)
// (r7 lesson: BN=256 = 96KB dbuf > 80KB budget -> 1 block/CU -> regression.)
// NEW vs r6: NSTEPS-templated fully-unrolled K-loop -> buffer parity and all
// LDS offsets compile-time (ds_read offset immediates, ~zero per-step VALU).
// Counted vmcnt (never 0 mid-loop). XOR swizzle verified 0-conflict (r3/r6).
template<int BN, int NSTEPS>
__global__ __launch_bounds__(512, 4)
void k_gemm(const u16* __restrict__ A, int lda, long long sA, long long sA2,
            const u16* __restrict__ Bp, int ldb, long long sB, long long sB2,
            float* __restrict__ outF, u16* __restrict__ outB,
            int ldc, long long sC, long long sC2,
            u16* __restrict__ outBT, int ldt, long long sT, long long sT2,
            int zdiv, const float* __restrict__ bias,
            const float* __restrict__ rowscale, int act)
{
  constexpr int BM = 128;
  constexpr int NB = BN / 64;               // B-tile gloads per stage
  constexpr int MI = (BN == 128) ? 2 : 1;
  constexpr int NI = 4;
  constexpr int WROWS = MI * 16;
  constexpr int ABYT = BM * 128;            // 16 KB (128 rows x 128 B)
  constexpr int BBYT = BN * 128;
  constexpr int BUF = ABYT + BBYT;
  const int z = blockIdx.z, zb = z / zdiv, zr = z - zb * zdiv;
  A  += (long long)zb * sA + (long long)zr * sA2;
  Bp += (long long)zb * sB + (long long)zr * sB2;
  const long long cof = (long long)zb * sC + (long long)zr * sC2;
  const long long tof = (long long)zb * sT + (long long)zr * sT2;
  const int bm = blockIdx.y * BM, bn = blockIdx.x * BN;
  __shared__ __align__(16) char lds[2 * BUF];
  const int tid = threadIdx.x;
  const int lane = tid & 63, wid = tid >> 6;
  const int wm = (BN == 128) ? (wid >> 1) : wid;
  const int wn = (BN == 128) ? (wid & 1) : 0;
  const int rowb = wm * WROWS, colb = wn * 64;

  f32x4 acc[MI][NI];
  const f32x4 fz = {0.f, 0.f, 0.f, 0.f};
  #pragma unroll
  for (int i = 0; i < MI; ++i)
    #pragma unroll
    for (int j = 0; j < NI; ++j) acc[i][j] = fz;

  // staging: thread t -> row t>>3, granule t&7; source granule ^= row&7;
  // LDS dest linear (wave-uniform base + lane*16).
  const int trow = tid >> 3;
  const int tg   = ((tid & 7) ^ (trow & 7)) * 8;
  const u16* gA  = A + (long long)(bm + trow) * lda + tg;
  const u16* gA2 = gA + (long long)64 * lda;
  const u16* gB  = Bp + (long long)(bn + trow) * ldb + tg;
  const u16* gB2 = gB + (long long)64 * ldb;       // only for BN==128

  // fragment read offsets: row' = base + i*16 + r; granule (4s+q) ^ (r&7)
  const int r = lane & 15, q = lane >> 4;
  const int c7 = r & 7;
  const int gs0 = ((q) ^ c7) << 4;
  const int gs1 = ((4 + q) ^ c7) << 4;
  int aoff[MI], boff[NI];
  #pragma unroll
  for (int i = 0; i < MI; ++i) aoff[i] = (rowb + i * 16 + r) * 128;
  #pragma unroll
  for (int j = 0; j < NI; ++j) boff[j] = (colb + j * 16 + r) * 128;

  auto stage = [&](int buf, int it) {
    char* la = lds + buf * BUF + wid * 1024;
    char* lb = la + ABYT;
    const int ko = it << 6;
    gload16(gA + ko, la);
    gload16(gA2 + ko, la + 8192);
    gload16(gB + ko, lb);
    if constexpr (BN == 128) gload16(gB2 + ko, lb + 8192);
  };

  stage(0, 0);
  #pragma unroll
  for (int it = 0; it < NSTEPS; ++it) {
    if (it + 1 < NSTEPS) {
      stage((it + 1) & 1, it + 1);
      if constexpr (BN == 128) asm volatile("s_waitcnt vmcnt(4)" ::: "memory");
      else                     asm volatile("s_waitcnt vmcnt(3)" ::: "memory");
    } else {
      asm volatile("s_waitcnt vmcnt(0)" ::: "memory");
    }
    __builtin_amdgcn_s_barrier();           // buf[it&1] landed for all waves
    __builtin_amdgcn_sched_barrier(0);
    const char* pa = lds + (it & 1) * BUF;
    const char* pb = pa + ABYT;
    #pragma unroll
    for (int s = 0; s < 2; ++s) {
      const int gso = s ? gs1 : gs0;
      bf16x8 af[MI], bv[NI];
      #pragma unroll
      for (int i = 0; i < MI; ++i) af[i] = *(const bf16x8*)(pa + aoff[i] + gso);
      #pragma unroll
      for (int j = 0; j < NI; ++j) bv[j] = *(const bf16x8*)(pb + boff[j] + gso);
      #pragma unroll
      for (int i = 0; i < MI; ++i)
        #pragma unroll
        for (int j = 0; j < NI; ++j)
          acc[i][j] = __builtin_amdgcn_mfma_f32_16x16x32_bf16(af[i], bv[j], acc[i][j], 0, 0, 0);
    }
    asm volatile("s_waitcnt lgkmcnt(0)" ::: "memory");  // this wave's ds_reads done
    __builtin_amdgcn_sched_barrier(0);
    __builtin_amdgcn_s_barrier();           // safe to overwrite buf[it&1]
  }

  const int fr = lane & 15, fq = lane >> 4;
  #pragma unroll
  for (int i = 0; i < MI; ++i) {
    const int r0 = bm + rowb + i * 16 + fq * 4;
    #pragma unroll
    for (int j = 0; j < NI; ++j) {
      const int cn = bn + colb + j * 16 + fr;
      const float bvv = bias ? bias[cn] : 0.f;
      float vv[4];
      #pragma unroll
      for (int t = 0; t < 4; ++t) {
        float v = acc[i][j][t] + bvv;
        if (rowscale) v *= rowscale[r0 + t];
        if (act) v = 0.5f * v * (1.f + tanhf(0.7978845608028654f * (v + 0.044715f * v * v * v)));
        vv[t] = v;
      }
      if (outF) {
        #pragma unroll
        for (int t = 0; t < 4; ++t) outF[cof + (long long)(r0 + t) * ldc + cn] = vv[t];
      }
      if (outB) {
        #pragma unroll
        for (int t = 0; t < 4; ++t) outB[cof + (long long)(r0 + t) * ldc + cn] = f2bf(vv[t]);
      }
      if (outBT) {
        u16x4 pk = {f2bf(vv[0]), f2bf(vv[1]), f2bf(vv[2]), f2bf(vv[3])};
        *(u16x4*)(outBT + tof + (long long)cn * ldt + r0) = pk;
      }
    }
  }
}

// ---------------- transpose + convert: in[R][C] fp32 -> out[C][R] bf16 ----------------
__global__ __launch_bounds__(256)
void k_tcvt(const float* __restrict__ in, u16* __restrict__ out, int R, int C)
{
  __shared__ float t[32][33];
  const int bx = blockIdx.x * 32, by = blockIdx.y * 32;
  const int tx = threadIdx.x & 31, ty = threadIdx.x >> 5;
  #pragma unroll
  for (int i = 0; i < 32; i += 8)
    t[ty + i][tx] = in[(long long)(by + ty + i) * C + bx + tx];
  __syncthreads();
  #pragma unroll
  for (int i = 0; i < 32; i += 8)
    out[(long long)(bx + ty + i) * R + by + tx] = f2bf(t[tx][ty + i]);
}

// ---------------- convert fp32 -> bf16 ----------------
__global__ __launch_bounds__(256)
void k_cvt(const float* __restrict__ in, u16* __restrict__ out, int n)
{
  int i = blockIdx.x * 256 + threadIdx.x;
  if (i < n) out[i] = f2bf(in[i]);
}

// ---------------- row softmax on bf16 in place (cols <= 1024) ----------------
__global__ __launch_bounds__(256)
void k_softmax_b16(u16* __restrict__ x, int cols, float scale)
{
  u16* p = x + (long long)blockIdx.x * cols;
  const int tid = threadIdx.x;
  __shared__ float red[256];
  float v[4];
  float m = -1e30f;
  #pragma unroll
  for (int i = 0; i < 4; ++i) {
    const int c = tid + (i << 8);
    v[i] = (c < cols) ? bf2f(p[c]) * scale : -1e30f;
    m = fmaxf(m, v[i]);
  }
  red[tid] = m; __syncthreads();
  for (int s = 128; s > 0; s >>= 1) { if (tid < s) red[tid] = fmaxf(red[tid], red[tid + s]); __syncthreads(); }
  m = red[0]; __syncthreads();
  float sum = 0.f;
  #pragma unroll
  for (int i = 0; i < 4; ++i) { v[i] = expf(v[i] - m); sum += v[i]; }
  red[tid] = sum; __syncthreads();
  for (int s = 128; s > 0; s >>= 1) { if (tid < s) red[tid] += red[tid + s]; __syncthreads(); }
  const float inv = 1.f / red[0];
  #pragma unroll
  for (int i = 0; i < 4; ++i) {
    const int c = tid + (i << 8);
    if (c < cols) p[c] = f2bf(v[i] * inv);
  }
}

// ---------------- layernorm: LN(x [+res])*g + b -> fp32 out (opt) + bf16 out (opt) ----------------
__global__ __launch_bounds__(256)
void k_layernorm(const float* __restrict__ x, const float* __restrict__ res,
                 const float* __restrict__ g, const float* __restrict__ b,
                 float* __restrict__ outF, u16* __restrict__ outB, int cols)
{
  const long long ro = (long long)blockIdx.x * cols;
  const float* px = x + ro;
  const float* pr = res ? res + ro : nullptr;
  __shared__ float red[256];
  const int tid = threadIdx.x;
  float s = 0.f;
  for (int c = tid; c < cols; c += 256) { float v = px[c] + (pr ? pr[c] : 0.f); s += v; }
  red[tid] = s; __syncthreads();
  for (int t = 128; t > 0; t >>= 1) { if (tid < t) red[tid] += red[tid + t]; __syncthreads(); }
  const float mean = red[0] / cols; __syncthreads();
  float s2 = 0.f;
  for (int c = tid; c < cols; c += 256) { float v = px[c] + (pr ? pr[c] : 0.f) - mean; s2 += v * v; }
  red[tid] = s2; __syncthreads();
  for (int t = 128; t > 0; t >>= 1) { if (tid < t) red[tid] += red[tid + t]; __syncthreads(); }
  const float inv = rsqrtf(red[0] / cols + 1e-5f);
  for (int c = tid; c < cols; c += 256) {
    float v = (px[c] + (pr ? pr[c] : 0.f) - mean) * inv * g[c] + b[c];
    if (outF) outF[ro + c] = v;
    if (outB) outB[ro + c] = f2bf(v);
  }
}

// ---------------- gate[row] = sigmoid(dot(x[row], w) + b0), 1 wave / row ----------------
__global__ __launch_bounds__(256)
void k_gate(const float* __restrict__ x, const float* __restrict__ w,
            const float* __restrict__ b0, float* __restrict__ out, int cols)
{
  const int lane = threadIdx.x & 63;
  const int wv = threadIdx.x >> 6;
  const long long row = (long long)blockIdx.x * 4 + wv;
  const float* p = x + row * cols;
  float s = 0.f;
  for (int c = lane; c < cols; c += 64) s += p[c] * w[c];
  #pragma unroll
  for (int off = 32; off > 0; off >>= 1) s += __shfl_down(s, off);
  if (lane == 0) out[row] = 1.0f / (1.0f + expf(-(s + b0[0])));
}

// ---------------- elementwise ----------------
__global__ __launch_bounds__(256)
void k_combine2(float* __restrict__ oF, u16* __restrict__ oB,
                const float* __restrict__ a, float sa, const float* __restrict__ b,
                const float* __restrict__ emb, int n, int Dm1)
{
  int i = blockIdx.x * 256 + threadIdx.x;
  if (i >= n) return;
  float v = sa * a[i];
  if (b) v += b[i];
  v += emb[i & Dm1];
  oF[i] = v; oB[i] = f2bf(v);
}

__global__ __launch_bounds__(256)
void k_gated_add(float* __restrict__ out, const float* __restrict__ h,
                 const float* __restrict__ r, const float* __restrict__ gate, int n, int Dv)
{
  int i = blockIdx.x * 256 + threadIdx.x;
  if (i >= n) return;
  out[i] = h[i] + gate[i / Dv] * r[i];
}

__global__ __launch_bounds__(256)
void k_add2(float* __restrict__ oF, u16* __restrict__ oB,
            const float* __restrict__ a, const float* __restrict__ b, int n)
{
  int i = blockIdx.x * 256 + threadIdx.x;
  if (i >= n) return;
  float v = a[i] + b[i];
  oF[i] = v; oB[i] = f2bf(v);
}

// ---------------- host ----------------
extern "C" void kernel_launch(void* const* d_in, const int* in_sizes, int n_in,
                              void* d_out, int out_size, void* d_ws, size_t ws_size,
                              hipStream_t stream)
{
  (void)in_sizes; (void)n_in; (void)out_size;
  const float* x        = (const float*)d_in[0];
  const float* cache0   = (const float*)d_in[1];
  const float* iter_emb = (const float*)d_in[2];
  const float* rq_w     = (const float*)d_in[3];
  const float* rg_w     = (const float*)d_in[4];
  const float* rg_b     = (const float*)d_in[5];
  const float* ck_w     = (const float*)d_in[6];
  const float* cv_w     = (const float*)d_in[7];
  const float* aq_w     = (const float*)d_in[8];
  const float* ak_w     = (const float*)d_in[9];
  const float* av_w     = (const float*)d_in[10];
  const float* ao_w     = (const float*)d_in[11];
  const float* aq_b     = (const float*)d_in[12];
  const float* ak_b     = (const float*)d_in[13];
  const float* av_b     = (const float*)d_in[14];
  const float* ao_b     = (const float*)d_in[15];
  const float* f1_w     = (const float*)d_in[16];
  const float* f1_b     = (const float*)d_in[17];
  const float* f2_w     = (const float*)d_in[18];
  const float* f2_b     = (const float*)d_in[19];
  const float* n1_g     = (const float*)d_in[20];
  const float* n1_b     = (const float*)d_in[21];
  const float* n2_g     = (const float*)d_in[22];
  const float* n2_b     = (const float*)d_in[23];
  const float* sq_w     = (const float*)d_in[24];
  const float* tk_w     = (const float*)d_in[25];
  const float* tv_w     = (const float*)d_in[26];
  const float* wg_w     = (const float*)d_in[27];
  const float* wg_b     = (const float*)d_in[28];
  const float* cq_w     = (const float*)d_in[29];
  const float* ck2_w    = (const float*)d_in[30];
  const float* cv2_w    = (const float*)d_in[31];
  const float* co_w     = (const float*)d_in[32];
  const float* cq_b     = (const float*)d_in[33];
  const float* ck2_b    = (const float*)d_in[34];
  const float* cv2_b    = (const float*)d_in[35];
  const float* co_b     = (const float*)d_in[36];
  const float* cn_g     = (const float*)d_in[37];
  const float* cn_b     = (const float*)d_in[38];
  // d_in[39] = max_iterations (fixed 2; schedule hardcoded for graph capture)

  float* out = (float*)d_out;

  // -------- workspace carve --------
  size_t off = 0;
  char* base = (char*)d_ws;
  auto allocF = [&](size_t n) { float* p = (float*)(base + off); off += n * 4; off = (off + 255) & ~(size_t)255; return p; };
  auto allocH = [&](size_t n) { u16* p = (u16*)(base + off); off += n * 2; off = (off + 255) & ~(size_t)255; return p; };

  float* hbuf  = allocF((size_t)BS_ * D_);
  float* henh  = allocF((size_t)BS_ * D_);
  float* hcomp = allocF((size_t)BS_ * D_);
  float* h2b   = allocF((size_t)BS_ * D_);
  float* tA    = allocF((size_t)BS_ * D_);
  float* gate  = allocF((size_t)BS_);
  float* ccnf  = allocF((size_t)BNS_ * DS_);
  float* updf  = allocF((size_t)BNS_ * DS_);
  float* coo   = allocF((size_t)BNS_ * DS_);
  float* ccwf  = allocF((size_t)BNS_ * DS_);
  u16* rqT  = allocH((size_t)D_ * D_);
  u16* ckT  = allocH((size_t)D_ * DS_);
  u16* cvT  = allocH((size_t)D_ * DS_);
  u16* aqT  = allocH((size_t)D_ * D_);
  u16* akT  = allocH((size_t)D_ * D_);
  u16* avT  = allocH((size_t)D_ * D_);
  u16* aoT  = allocH((size_t)D_ * D_);
  u16* f1T  = allocH((size_t)DFF_ * D_);
  u16* f2T  = allocH((size_t)D_ * DFF_);
  u16* sqT  = allocH((size_t)DS_ * DS_);
  u16* tkT  = allocH((size_t)DS_ * D_);
  u16* tvTw = allocH((size_t)DS_ * D_);
  u16* cqT  = allocH((size_t)DS_ * DS_);
  u16* ck2T = allocH((size_t)DS_ * DS_);
  u16* cv2T = allocH((size_t)DS_ * DS_);
  u16* coT  = allocH((size_t)DS_ * DS_);
  u16* bb1  = allocH((size_t)BS_ * D_);
  u16* bb2  = allocH((size_t)BS_ * D_);
  u16* bb3  = allocH((size_t)BS_ * D_);
  u16* bb4  = allocH((size_t)BS_ * D_);
  u16* bb5  = allocH((size_t)B_ * H_ * S_ * S_);
  u16* cc0b = allocH((size_t)BNS_ * DS_);
  u16* ccwb = allocH((size_t)BNS_ * DS_);
  u16* sqb  = allocH((size_t)BNS_ * DS_);
  u16* tkb  = allocH((size_t)BS_ * DS_);
  u16* tvTb = allocH((size_t)DS_ * BS_);
  u16* ccnb = allocH((size_t)BNS_ * DS_);
  u16* cqb  = allocH((size_t)BNS_ * DS_);
  u16* ck2b = allocH((size_t)BNS_ * DS_);
  u16* cv2Tb= allocH((size_t)DS_ * BNS_);
  u16* csab = allocH((size_t)BNS_ * DS_);
  if (off > ws_size) return;

  auto gemm = [&](int M, int N, int K, int z, int zdiv,
                  const u16* Ap, int lda, long long sa, long long sa2,
                  const u16* Bq, int ldb, long long sb, long long sb2,
                  float* oF, u16* oB, int ldc, long long sc, long long sc2,
                  u16* oBT, int ldt, long long st, long long st2,
                  const float* bias, const float* rsc, int act) {
    const int ns = K >> 6;
#define GARGS Ap, lda, sa, sa2, Bq, ldb, sb, sb2, oF, oB, ldc, sc, sc2, oBT, ldt, st, st2, zdiv, bias, rsc, act
    const long long blocks128 = (N % 128 == 0) ? (long long)(N / 128) * (M / 128) * z : 0;
    if (N % 128 == 0 && blocks128 >= 256) {
      dim3 g(N / 128, M / 128, z);
      if      (ns == 4)  k_gemm<128, 4><<<g, 512, 0, stream>>>(GARGS);
      else if (ns == 8)  k_gemm<128, 8><<<g, 512, 0, stream>>>(GARGS);
      else if (ns == 16) k_gemm<128, 16><<<g, 512, 0, stream>>>(GARGS);
      else if (ns == 64) k_gemm<128, 64><<<g, 512, 0, stream>>>(GARGS);
    } else {
      dim3 g(N / 64, M / 128, z);
      if      (ns == 1)  k_gemm<64, 1><<<g, 512, 0, stream>>>(GARGS);
      else if (ns == 4)  k_gemm<64, 4><<<g, 512, 0, stream>>>(GARGS);
      else if (ns == 5)  k_gemm<64, 5><<<g, 512, 0, stream>>>(GARGS);
      else if (ns == 8)  k_gemm<64, 8><<<g, 512, 0, stream>>>(GARGS);
      else if (ns == 16) k_gemm<64, 16><<<g, 512, 0, stream>>>(GARGS);
      else if (ns == 64) k_gemm<64, 64><<<g, 512, 0, stream>>>(GARGS);
    }
#undef GARGS
  };
  auto tcvt = [&](const float* in, u16* o, int R, int C) {
    dim3 g(C / 32, R / 32);
    k_tcvt<<<g, 256, 0, stream>>>(in, o, R, C);
  };
  auto lnorm = [&](const float* xp, const float* rp, const float* g, const float* b,
                   float* oF, u16* oB, int rows, int cols) {
    k_layernorm<<<rows, 256, 0, stream>>>(xp, rp, g, b, oF, oB, cols);
  };
  auto eg = [](int n) { return dim3((n + 255) / 256); };

  // ---- weight prep ----
  tcvt(rq_w, rqT, D_, D_);
  tcvt(ck_w, ckT, DS_, D_);
  tcvt(cv_w, cvT, DS_, D_);
  tcvt(aq_w, aqT, D_, D_);
  tcvt(ak_w, akT, D_, D_);
  tcvt(av_w, avT, D_, D_);
  tcvt(ao_w, aoT, D_, D_);
  tcvt(f1_w, f1T, D_, DFF_);
  tcvt(f2_w, f2T, DFF_, D_);
  tcvt(sq_w, sqT, DS_, DS_);
  tcvt(tk_w, tkT, D_, DS_);
  tcvt(tv_w, tvTw, D_, DS_);
  tcvt(cq_w, cqT, DS_, DS_);
  tcvt(ck2_w, ck2T, DS_, DS_);
  tcvt(cv2_w, cv2T, DS_, DS_);
  tcvt(co_w, coT, DS_, DS_);
  k_cvt<<<eg(BNS_ * DS_), 256, 0, stream>>>(cache0, cc0b, BNS_ * DS_);

  // ---- mem_read ----
  auto mem_read = [&](const float* h_f, const u16* h_b, const u16* cc_b, float* o_henh) {
    gemm(BS_, D_, D_, 1, 1, h_b, D_, 0, 0, rqT, D_, 0, 0,
         nullptr, bb2, D_, 0, 0, nullptr, 0, 0, 0, nullptr, nullptr, 0);            // q
    gemm(BNS_, D_, DS_, 1, 1, cc_b, DS_, 0, 0, ckT, DS_, 0, 0,
         nullptr, bb3, D_, 0, 0, nullptr, 0, 0, 0, nullptr, nullptr, 0);            // k
    gemm(BNS_, D_, DS_, 1, 1, cc_b, DS_, 0, 0, cvT, DS_, 0, 0,
         nullptr, nullptr, 0, 0, 0, bb4, BNS_, 0, 0, nullptr, nullptr, 0);          // v^T
    gemm(S_, NSLOT_, D_, B_, 1, bb2, D_, (long long)S_ * D_, 0,
         bb3, D_, (long long)NSLOT_ * D_, 0,
         nullptr, bb5, NSLOT_, (long long)S_ * NSLOT_, 0,
         nullptr, 0, 0, 0, nullptr, nullptr, 0);                                    // q k^T
    k_softmax_b16<<<B_ * S_, 256, 0, stream>>>(bb5, NSLOT_, 0.03125f);
    gemm(S_, D_, NSLOT_, B_, 1, bb5, NSLOT_, (long long)S_ * NSLOT_, 0,
         bb4, BNS_, NSLOT_, 0,
         tA, nullptr, D_, (long long)S_ * D_, 0,
         nullptr, 0, 0, 0, nullptr, nullptr, 0);                                    // readout
    k_gate<<<BS_ / 4, 256, 0, stream>>>(h_f, rg_w, rg_b, gate, D_);
    k_gated_add<<<eg(BS_ * D_), 256, 0, stream>>>(o_henh, h_f, tA, gate, BS_ * D_, D_);
  };

  // ---- compute_block ----
  auto compute_block = [&](const float* he, float* oF, u16* oB) {
    lnorm(he, nullptr, n1_g, n1_b, nullptr, bb1, BS_, D_);
    gemm(BS_, D_, D_, 1, 1, bb1, D_, 0, 0, aqT, D_, 0, 0,
         nullptr, bb2, D_, 0, 0, nullptr, 0, 0, 0, aq_b, nullptr, 0);               // qa
    gemm(BS_, D_, D_, 1, 1, bb1, D_, 0, 0, akT, D_, 0, 0,
         nullptr, bb3, D_, 0, 0, nullptr, 0, 0, 0, ak_b, nullptr, 0);               // ka
    gemm(BS_, D_, D_, 1, 1, bb1, D_, 0, 0, avT, D_, 0, 0,
         nullptr, nullptr, 0, 0, 0, bb4, BS_, 0, 0, av_b, nullptr, 0);              // va^T
    gemm(S_, S_, HD_, B_ * H_, H_,
         bb2, D_, (long long)S_ * D_, HD_,
         bb3, D_, (long long)S_ * D_, HD_,
         nullptr, bb5, S_, (long long)H_ * S_ * S_, (long long)S_ * S_,
         nullptr, 0, 0, 0, nullptr, nullptr, 0);                                    // scores
    k_softmax_b16<<<B_ * H_ * S_, 256, 0, stream>>>(bb5, S_, 0.0625f);
    gemm(S_, HD_, S_, B_ * H_, H_,
         bb5, S_, (long long)H_ * S_ * S_, (long long)S_ * S_,
         bb4, BS_, S_, (long long)HD_ * BS_,
         nullptr, bb2, D_, (long long)S_ * D_, HD_,
         nullptr, 0, 0, 0, nullptr, nullptr, 0);                                    // attnv
    gemm(BS_, D_, D_, 1, 1, bb2, D_, 0, 0, aoT, D_, 0, 0,
         tA, nullptr, D_, 0, 0, nullptr, 0, 0, 0, ao_b, nullptr, 0);                // attno
    lnorm(he, tA, n1_g, n1_b, h2b, bb1, BS_, D_);
    gemm(BS_, DFF_, D_, 1, 1, bb1, D_, 0, 0, f1T, D_, 0, 0,
         nullptr, bb5, DFF_, 0, 0, nullptr, 0, 0, 0, f1_b, nullptr, 1);             // f1+gelu
    gemm(BS_, D_, DFF_, 1, 1, bb5, DFF_, 0, 0, f2T, DFF_, 0, 0,
         tA, nullptr, D_, 0, 0, nullptr, 0, 0, 0, f2_b, nullptr, 0);                // f2
    lnorm(h2b, tA, n2_g, n2_b, oF, oB, BS_, D_);
  };

  // ---- mem_write + cache self-attn (skipped in last iter) ----
  auto mem_write_csa = [&](const float* hc_f, const u16* hc_b,
                           const float* ccin_f, const u16* ccin_b) {
    gemm(BNS_, DS_, DS_, 1, 1, ccin_b, DS_, 0, 0, sqT, DS_, 0, 0,
         nullptr, sqb, DS_, 0, 0, nullptr, 0, 0, 0, nullptr, nullptr, 0);           // sq
    gemm(BS_, DS_, D_, 1, 1, hc_b, D_, 0, 0, tkT, D_, 0, 0,
         nullptr, tkb, DS_, 0, 0, nullptr, 0, 0, 0, nullptr, nullptr, 0);           // tk
    k_gate<<<BS_ / 4, 256, 0, stream>>>(hc_f, wg_w, wg_b, gate, D_);
    gemm(BS_, DS_, D_, 1, 1, hc_b, D_, 0, 0, tvTw, D_, 0, 0,
         nullptr, nullptr, 0, 0, 0, tvTb, BS_, 0, 0, nullptr, gate, 0);             // (gate*tv)^T
    gemm(NSLOT_, S_, DS_, B_, 1, sqb, DS_, (long long)NSLOT_ * DS_, 0,
         tkb, DS_, (long long)S_ * DS_, 0,
         nullptr, bb5, S_, (long long)NSLOT_ * S_, 0,
         nullptr, 0, 0, 0, nullptr, nullptr, 0);                                    // slot scores
    k_softmax_b16<<<B_ * NSLOT_, 256, 0, stream>>>(bb5, S_, 0.05590169943749474f);
    gemm(NSLOT_, DS_, S_, B_, 1, bb5, S_, (long long)NSLOT_ * S_, 0,
         tvTb, BS_, S_, 0,
         updf, nullptr, DS_, (long long)NSLOT_ * DS_, 0,
         nullptr, 0, 0, 0, nullptr, nullptr, 0);                                    // upd
    k_add2<<<eg(BNS_ * DS_), 256, 0, stream>>>(ccnf, ccnb, ccin_f, updf, BNS_ * DS_);
    gemm(BNS_, DS_, DS_, 1, 1, ccnb, DS_, 0, 0, cqT, DS_, 0, 0,
         nullptr, cqb, DS_, 0, 0, nullptr, 0, 0, 0, cq_b, nullptr, 0);              // cq
    gemm(BNS_, DS_, DS_, 1, 1, ccnb, DS_, 0, 0, ck2T, DS_, 0, 0,
         nullptr, ck2b, DS_, 0, 0, nullptr, 0, 0, 0, ck2_b, nullptr, 0);            // ck
    gemm(BNS_, DS_, DS_, 1, 1, ccnb, DS_, 0, 0, cv2T, DS_, 0, 0,
         nullptr, nullptr, 0, 0, 0, cv2Tb, BNS_, 0, 0, cv2_b, nullptr, 0);          // cv^T
    gemm(NSLOT_, NSLOT_, CHD_, B_ * CH_, CH_,
         cqb, DS_, (long long)NSLOT_ * DS_, CHD_,
         ck2b, DS_, (long long)NSLOT_ * DS_, CHD_,
         nullptr, bb5, NSLOT_, (long long)CH_ * NSLOT_ * NSLOT_, (long long)NSLOT_ * NSLOT_,
         nullptr, 0, 0, 0, nullptr, nullptr, 0);                                    // csa scores
    k_softmax_b16<<<B_ * CH_ * NSLOT_, 256, 0, stream>>>(bb5, NSLOT_, 0.125f);
    gemm(NSLOT_, CHD_, NSLOT_, B_ * CH_, CH_,
         bb5, NSLOT_, (long long)CH_ * NSLOT_ * NSLOT_, (long long)NSLOT_ * NSLOT_,
         cv2Tb, BNS_, NSLOT_, (long long)CHD_ * BNS_,
         nullptr, csab, DS_, (long long)NSLOT_ * DS_, CHD_,
         nullptr, 0, 0, 0, nullptr, nullptr, 0);                                    // csa pv
    gemm(BNS_, DS_, DS_, 1, 1, csab, DS_, 0, 0, coT, DS_, 0, 0,
         coo, nullptr, DS_, 0, 0, nullptr, 0, 0, 0, co_b, nullptr, 0);              // co
    lnorm(ccnf, coo, cn_g, cn_b, ccwf, ccwb, BNS_, DS_);
  };

  // ================= iteration 0 =================
  k_combine2<<<eg(BS_ * D_), 256, 0, stream>>>(hbuf, bb1, x, 1.0f, nullptr, iter_emb, BS_ * D_, D_ - 1);
  mem_read(hbuf, bb1, cc0b, henh);
  compute_block(henh, hcomp, bb3);
  mem_write_csa(hcomp, bb3, cache0, cc0b);

  // ================= iteration 1 (last: cache update dead, skipped) =================
  k_combine2<<<eg(BS_ * D_), 256, 0, stream>>>(hbuf, bb1, hcomp, 2.0f, x, iter_emb + D_, BS_ * D_, D_ - 1);
  mem_read(hbuf, bb1, ccwb, henh);
  compute_block(henh, out, nullptr);
}

// Round 9
// 578.299 us; speedup vs baseline: 1.5058x; 1.2805x over previous
//
#include <hip/hip_runtime.h>
#include <cstdint>

// ---------------- problem constants ----------------
constexpr int B_ = 2, S_ = 1024, D_ = 1024, DS_ = 320, NSLOT_ = 512;
constexpr int H_ = 4, CH_ = 5, DFF_ = 4096;
constexpr int HD_ = D_ / H_;      // 256
constexpr int CHD_ = DS_ / CH_;   // 64
constexpr int BS_ = B_ * S_;      // 2048
constexpr int BNS_ = B_ * NSLOT_; // 1024

typedef unsigned short u16;
typedef __attribute__((ext_vector_type(8))) short bf16x8;
typedef __attribute__((ext_vector_type(4))) float f32x4;
typedef __attribute__((ext_vector_type(4))) u16 u16x4;
typedef long long ll;

__device__ __forceinline__ u16 f2bf(float f) {
  unsigned u = __float_as_uint(f);
  return (u16)((u + 0x7FFFu + ((u >> 16) & 1u)) >> 16);  // RNE
}
__device__ __forceinline__ float bf2f(u16 h) { return __uint_as_float((unsigned)h << 16); }

__device__ __forceinline__ void gload16(const void* g, void* l) {
  __builtin_amdgcn_global_load_lds((const __attribute__((address_space(1))) void*)g,
                                   (__attribute__((address_space(3))) void*)l, 16, 0, 0);
}

// ---------------- bf16 MFMA GEMM: C[m,n] = sum_k A[m,k]*B[n,k] ----------------
// r6-proven core: BM=128, BK=64, 512 thr, dynamic K loop, double-buffered,
// counted vmcnt, XOR-swizzled LDS (0 bank conflicts, verified r3/r6).
//   BN=128: waves 4x2, per-wave 32x64, LDS 64KB (2 blocks/CU)
//   BN=64 : waves 8x1, per-wave 16x64, LDS 48KB (3 blocks/CU)
// Column-split epilogue: cn < splitcol -> outF/outB normal (ldc);
//                        cn >= splitcol -> outBT transposed at cn-splitcol (ldt).
// rowscale applies only when cn >= rscfrom.
template<int BN>
__global__ __launch_bounds__(512, 4)
void k_gemm(const u16* __restrict__ A, int lda, ll sA, ll sA2,
            const u16* __restrict__ Bp, int ldb, ll sB, ll sB2,
            float* __restrict__ outF, u16* __restrict__ outB,
            int ldc, ll sC, ll sC2,
            u16* __restrict__ outBT, int ldt, ll sT, ll sT2,
            int K, int zdiv, const float* __restrict__ bias,
            const float* __restrict__ rowscale, int rscfrom,
            int splitcol, int act)
{
  constexpr int BM = 128;
  constexpr int MI = (BN == 128) ? 2 : 1;
  constexpr int NI = 4;
  constexpr int WROWS = MI * 16;
  constexpr int ABYT = BM * 128;            // 16 KB
  constexpr int BBYT = BN * 128;
  constexpr int BUF = ABYT + BBYT;
  const int z = blockIdx.z, zb = z / zdiv, zr = z - zb * zdiv;
  A  += (ll)zb * sA + (ll)zr * sA2;
  Bp += (ll)zb * sB + (ll)zr * sB2;
  const ll cof = (ll)zb * sC + (ll)zr * sC2;
  const ll tof = (ll)zb * sT + (ll)zr * sT2;
  const int bm = blockIdx.y * BM, bn = blockIdx.x * BN;
  __shared__ __align__(16) char lds[2 * BUF];
  const int tid = threadIdx.x;
  const int lane = tid & 63, wid = tid >> 6;
  const int wm = (BN == 128) ? (wid >> 1) : wid;
  const int wn = (BN == 128) ? (wid & 1) : 0;
  const int rowb = wm * WROWS, colb = wn * 64;

  f32x4 acc[MI][NI];
  const f32x4 fz = {0.f, 0.f, 0.f, 0.f};
  #pragma unroll
  for (int i = 0; i < MI; ++i)
    #pragma unroll
    for (int j = 0; j < NI; ++j) acc[i][j] = fz;

  // staging: thread t -> row t>>3, granule t&7; source granule ^= row&7;
  // LDS dest linear (wave-uniform base + lane*16).
  const int trow = tid >> 3;
  const int tg   = ((tid & 7) ^ (trow & 7)) * 8;
  const u16* gA  = A + (ll)(bm + trow) * lda + tg;
  const u16* gA2 = gA + (ll)64 * lda;
  const u16* gB  = Bp + (ll)(bn + trow) * ldb + tg;
  const u16* gB2 = gB + (ll)64 * ldb;       // only for BN==128

  // fragment read offsets: row' = base + i*16 + r; granule (4s+q) ^ (r&7)
  const int r = lane & 15, q = lane >> 4;
  const int c7 = r & 7;
  const int gs0 = ((q) ^ c7) << 4;
  const int gs1 = ((4 + q) ^ c7) << 4;
  int aoff[MI], boff[NI];
  #pragma unroll
  for (int i = 0; i < MI; ++i) aoff[i] = (rowb + i * 16 + r) * 128;
  #pragma unroll
  for (int j = 0; j < NI; ++j) boff[j] = (colb + j * 16 + r) * 128;

  auto stage = [&](int buf, int it) {
    char* la = lds + buf * BUF + wid * 1024;
    char* lb = la + ABYT;
    const int ko = it << 6;
    gload16(gA + ko, la);
    gload16(gA2 + ko, la + 8192);
    gload16(gB + ko, lb);
    if constexpr (BN == 128) gload16(gB2 + ko, lb + 8192);
  };

  const int nsteps = K >> 6;
  stage(0, 0);
  int bufp = 0;
  for (int it = 0; it < nsteps; ++it) {
    if (it + 1 < nsteps) {
      stage(bufp ^ 1, it + 1);
      if constexpr (BN == 128) asm volatile("s_waitcnt vmcnt(4)" ::: "memory");
      else                     asm volatile("s_waitcnt vmcnt(3)" ::: "memory");
    } else {
      asm volatile("s_waitcnt vmcnt(0)" ::: "memory");
    }
    __builtin_amdgcn_s_barrier();           // buf[bufp] landed for all waves
    __builtin_amdgcn_sched_barrier(0);
    const char* pa = lds + bufp * BUF;
    const char* pb = pa + ABYT;
    #pragma unroll
    for (int s = 0; s < 2; ++s) {
      const int gso = s ? gs1 : gs0;
      bf16x8 af[MI], bv[NI];
      #pragma unroll
      for (int i = 0; i < MI; ++i) af[i] = *(const bf16x8*)(pa + aoff[i] + gso);
      #pragma unroll
      for (int j = 0; j < NI; ++j) bv[j] = *(const bf16x8*)(pb + boff[j] + gso);
      #pragma unroll
      for (int i = 0; i < MI; ++i)
        #pragma unroll
        for (int j = 0; j < NI; ++j)
          acc[i][j] = __builtin_amdgcn_mfma_f32_16x16x32_bf16(af[i], bv[j], acc[i][j], 0, 0, 0);
    }
    asm volatile("s_waitcnt lgkmcnt(0)" ::: "memory");  // this wave's ds_reads done
    __builtin_amdgcn_sched_barrier(0);
    __builtin_amdgcn_s_barrier();           // safe to overwrite buf[bufp]
    bufp ^= 1;
  }

  const int fr = lane & 15, fq = lane >> 4;
  #pragma unroll
  for (int i = 0; i < MI; ++i) {
    const int r0 = bm + rowb + i * 16 + fq * 4;
    #pragma unroll
    for (int j = 0; j < NI; ++j) {
      const int cn = bn + colb + j * 16 + fr;
      const float bvv = bias ? bias[cn] : 0.f;
      const bool doRs = rowscale && (cn >= rscfrom);
      float vv[4];
      #pragma unroll
      for (int t = 0; t < 4; ++t) {
        float v = acc[i][j][t] + bvv;
        if (doRs) v *= rowscale[r0 + t];
        if (act) v = 0.5f * v * (1.f + tanhf(0.7978845608028654f * (v + 0.044715f * v * v * v)));
        vv[t] = v;
      }
      if (cn < splitcol) {
        if (outF) {
          #pragma unroll
          for (int t = 0; t < 4; ++t) outF[cof + (ll)(r0 + t) * ldc + cn] = vv[t];
        }
        if (outB) {
          #pragma unroll
          for (int t = 0; t < 4; ++t) outB[cof + (ll)(r0 + t) * ldc + cn] = f2bf(vv[t]);
        }
      } else {
        u16x4 pk = {f2bf(vv[0]), f2bf(vv[1]), f2bf(vv[2]), f2bf(vv[3])};
        *(u16x4*)(outBT + tof + (ll)(cn - splitcol) * ldt + r0) = pk;
      }
    }
  }
}

// ---------------- transpose + convert: in[R][C] fp32 -> out[C][R] bf16 ----------------
__global__ __launch_bounds__(256)
void k_tcvt(const float* __restrict__ in, u16* __restrict__ out, int R, int C)
{
  __shared__ float t[32][33];
  const int bx = blockIdx.x * 32, by = blockIdx.y * 32;
  const int tx = threadIdx.x & 31, ty = threadIdx.x >> 5;
  #pragma unroll
  for (int i = 0; i < 32; i += 8)
    t[ty + i][tx] = in[(ll)(by + ty + i) * C + bx + tx];
  __syncthreads();
  #pragma unroll
  for (int i = 0; i < 32; i += 8)
    out[(ll)(bx + ty + i) * R + by + tx] = f2bf(t[tx][ty + i]);
}

__global__ __launch_bounds__(256)
void k_cvt(const float* __restrict__ in, u16* __restrict__ out, int n)
{
  int i = blockIdx.x * 256 + threadIdx.x;
  if (i < n) out[i] = f2bf(in[i]);
}

// concat 3 fp32 vectors
__global__ __launch_bounds__(256)
void k_cat3f(float* __restrict__ dst, const float* __restrict__ a, int na,
             const float* __restrict__ b, int nb, const float* __restrict__ c, int nc)
{
  int i = blockIdx.x * 256 + threadIdx.x;
  if (i < na) dst[i] = a[i];
  else if (i < na + nb) dst[i] = b[i - na];
  else if (i < na + nb + nc) dst[i] = c[i - na - nb];
}

// ---------------- row softmax on bf16 in place (cols <= 1024) ----------------
__global__ __launch_bounds__(256)
void k_softmax_b16(u16* __restrict__ x, int cols, float scale)
{
  u16* p = x + (ll)blockIdx.x * cols;
  const int tid = threadIdx.x;
  __shared__ float red[256];
  float v[4];
  float m = -1e30f;
  #pragma unroll
  for (int i = 0; i < 4; ++i) {
    const int c = tid + (i << 8);
    v[i] = (c < cols) ? bf2f(p[c]) * scale : -1e30f;
    m = fmaxf(m, v[i]);
  }
  red[tid] = m; __syncthreads();
  for (int s = 128; s > 0; s >>= 1) { if (tid < s) red[tid] = fmaxf(red[tid], red[tid + s]); __syncthreads(); }
  m = red[0]; __syncthreads();
  float sum = 0.f;
  #pragma unroll
  for (int i = 0; i < 4; ++i) { v[i] = expf(v[i] - m); sum += v[i]; }
  red[tid] = sum; __syncthreads();
  for (int s = 128; s > 0; s >>= 1) { if (tid < s) red[tid] += red[tid + s]; __syncthreads(); }
  const float inv = 1.f / red[0];
  #pragma unroll
  for (int i = 0; i < 4; ++i) {
    const int c = tid + (i << 8);
    if (c < cols) p[c] = f2bf(v[i] * inv);
  }
}

// ---------------- layernorm: LN(x [+res][+res2][+rbias])*g + b ----------------
__global__ __launch_bounds__(256)
void k_layernorm(const float* __restrict__ x, const float* __restrict__ res,
                 const float* __restrict__ res2, const float* __restrict__ rbias,
                 const float* __restrict__ g, const float* __restrict__ b,
                 float* __restrict__ outF, u16* __restrict__ outB, int cols)
{
  const ll ro = (ll)blockIdx.x * cols;
  const float* px = x + ro;
  const float* pr = res ? res + ro : nullptr;
  const float* p2 = res2 ? res2 + ro : nullptr;
  __shared__ float red[256];
  const int tid = threadIdx.x;
  auto val = [&](int c) {
    float v = px[c];
    if (pr) v += pr[c];
    if (p2) v += p2[c];
    if (rbias) v += rbias[c];
    return v;
  };
  float s = 0.f;
  for (int c = tid; c < cols; c += 256) s += val(c);
  red[tid] = s; __syncthreads();
  for (int t = 128; t > 0; t >>= 1) { if (tid < t) red[tid] += red[tid + t]; __syncthreads(); }
  const float mean = red[0] / cols; __syncthreads();
  float s2 = 0.f;
  for (int c = tid; c < cols; c += 256) { float v = val(c) - mean; s2 += v * v; }
  red[tid] = s2; __syncthreads();
  for (int t = 128; t > 0; t >>= 1) { if (tid < t) red[tid] += red[tid + t]; __syncthreads(); }
  const float inv = rsqrtf(red[0] / cols + 1e-5f);
  for (int c = tid; c < cols; c += 256) {
    float v = (val(c) - mean) * inv * g[c] + b[c];
    if (outF) outF[ro + c] = v;
    if (outB) outB[ro + c] = f2bf(v);
  }
}

// ---------------- gate[row] = sigmoid(dot(x[row], w) + b0), 1 wave / row ----------------
__global__ __launch_bounds__(256)
void k_gate(const float* __restrict__ x, const float* __restrict__ w,
            const float* __restrict__ b0, float* __restrict__ out, int cols)
{
  const int lane = threadIdx.x & 63;
  const int wv = threadIdx.x >> 6;
  const ll row = (ll)blockIdx.x * 4 + wv;
  const float* p = x + row * cols;
  float s = 0.f;
  for (int c = lane; c < cols; c += 64) s += p[c] * w[c];
  #pragma unroll
  for (int off = 32; off > 0; off >>= 1) s += __shfl_down(s, off);
  if (lane == 0) out[row] = 1.0f / (1.0f + expf(-(s + b0[0])));
}

// ---------------- elementwise ----------------
__global__ __launch_bounds__(256)
void k_combine2(float* __restrict__ oF, u16* __restrict__ oB,
                const float* __restrict__ a, float sa, const float* __restrict__ b,
                const float* __restrict__ emb, int n, int Dm1)
{
  int i = blockIdx.x * 256 + threadIdx.x;
  if (i >= n) return;
  float v = sa * a[i];
  if (b) v += b[i];
  v += emb[i & Dm1];
  oF[i] = v; oB[i] = f2bf(v);
}

__global__ __launch_bounds__(256)
void k_gated_add(float* __restrict__ out, const float* __restrict__ h,
                 const float* __restrict__ r, const float* __restrict__ gate, int n, int Dv)
{
  int i = blockIdx.x * 256 + threadIdx.x;
  if (i >= n) return;
  out[i] = h[i] + gate[i / Dv] * r[i];
}

__global__ __launch_bounds__(256)
void k_add2(float* __restrict__ oF, u16* __restrict__ oB,
            const float* __restrict__ a, const float* __restrict__ b, int n)
{
  int i = blockIdx.x * 256 + threadIdx.x;
  if (i >= n) return;
  float v = a[i] + b[i];
  oF[i] = v; oB[i] = f2bf(v);
}

// ---------------- host ----------------
extern "C" void kernel_launch(void* const* d_in, const int* in_sizes, int n_in,
                              void* d_out, int out_size, void* d_ws, size_t ws_size,
                              hipStream_t stream)
{
  (void)in_sizes; (void)n_in; (void)out_size;
  const float* x        = (const float*)d_in[0];
  const float* cache0   = (const float*)d_in[1];
  const float* iter_emb = (const float*)d_in[2];
  const float* rq_w     = (const float*)d_in[3];
  const float* rg_w     = (const float*)d_in[4];
  const float* rg_b     = (const float*)d_in[5];
  const float* ck_w     = (const float*)d_in[6];
  const float* cv_w     = (const float*)d_in[7];
  const float* aq_w     = (const float*)d_in[8];
  const float* ak_w     = (const float*)d_in[9];
  const float* av_w     = (const float*)d_in[10];
  const float* ao_w     = (const float*)d_in[11];
  const float* aq_b     = (const float*)d_in[12];
  const float* ak_b     = (const float*)d_in[13];
  const float* av_b     = (const float*)d_in[14];
  const float* ao_b     = (const float*)d_in[15];
  const float* f1_w     = (const float*)d_in[16];
  const float* f1_b     = (const float*)d_in[17];
  const float* f2_w     = (const float*)d_in[18];
  const float* f2_b     = (const float*)d_in[19];
  const float* n1_g     = (const float*)d_in[20];
  const float* n1_b     = (const float*)d_in[21];
  const float* n2_g     = (const float*)d_in[22];
  const float* n2_b     = (const float*)d_in[23];
  const float* sq_w     = (const float*)d_in[24];
  const float* tk_w     = (const float*)d_in[25];
  const float* tv_w     = (const float*)d_in[26];
  const float* wg_w     = (const float*)d_in[27];
  const float* wg_b     = (const float*)d_in[28];
  const float* cq_w     = (const float*)d_in[29];
  const float* ck2_w    = (const float*)d_in[30];
  const float* cv2_w    = (const float*)d_in[31];
  const float* co_w     = (const float*)d_in[32];
  const float* cq_b     = (const float*)d_in[33];
  const float* ck2_b    = (const float*)d_in[34];
  const float* cv2_b    = (const float*)d_in[35];
  const float* co_b     = (const float*)d_in[36];
  const float* cn_g     = (const float*)d_in[37];
  const float* cn_b     = (const float*)d_in[38];
  // d_in[39] = max_iterations (fixed 2; schedule hardcoded for graph capture)

  float* out = (float*)d_out;

  // -------- workspace carve --------
  size_t off = 0;
  char* base = (char*)d_ws;
  auto allocF = [&](size_t n) { float* p = (float*)(base + off); off += n * 4; off = (off + 255) & ~(size_t)255; return p; };
  auto allocH = [&](size_t n) { u16* p = (u16*)(base + off); off += n * 2; off = (off + 255) & ~(size_t)255; return p; };

  float* hbuf  = allocF((size_t)BS_ * D_);
  float* henh  = allocF((size_t)BS_ * D_);
  float* hcomp = allocF((size_t)BS_ * D_);
  float* h2b   = allocF((size_t)BS_ * D_);
  float* tA    = allocF((size_t)2 * BS_ * D_);   // fp32 temp + f2 split-K partials
  float* gate  = allocF((size_t)BS_);
  float* ccnf  = allocF((size_t)BNS_ * DS_);
  float* updf  = allocF((size_t)BNS_ * DS_);
  float* coo   = allocF((size_t)BNS_ * DS_);
  float* ccwf  = allocF((size_t)BNS_ * DS_);
  float* qkvb  = allocF(3 * D_);
  float* cqkvb = allocF(3 * DS_);
  // bf16 weights [N][K]; stacked groups MUST stay adjacent (fused GEMMs):
  u16* rqT  = allocH((size_t)D_ * D_);
  u16* ckT  = allocH((size_t)D_ * DS_);   // kvT = ckT (ck|cv stacked, 2048x320)
  u16* cvT  = allocH((size_t)D_ * DS_);
  u16* aqT  = allocH((size_t)D_ * D_);    // qkvT = aqT (aq|ak|av stacked, 3072x1024)
  u16* akT  = allocH((size_t)D_ * D_);
  u16* avT  = allocH((size_t)D_ * D_);
  u16* aoT  = allocH((size_t)D_ * D_);
  u16* f1T  = allocH((size_t)DFF_ * D_);
  u16* f2T  = allocH((size_t)D_ * DFF_);
  u16* sqT  = allocH((size_t)DS_ * DS_);
  u16* tkT  = allocH((size_t)DS_ * D_);   // tktvT = tkT (tk|tv stacked, 640x1024)
  u16* tvTw = allocH((size_t)DS_ * D_);
  u16* cqT  = allocH((size_t)DS_ * DS_);  // cqkvT = cqT (cq|ck|cv stacked, 960x320)
  u16* ck2T = allocH((size_t)DS_ * DS_);
  u16* cv2T = allocH((size_t)DS_ * DS_);
  u16* coT  = allocH((size_t)DS_ * DS_);
  // bf16 activations
  u16* bb1  = allocH((size_t)BS_ * D_);
  u16* bb2  = allocH((size_t)BS_ * D_);
  u16* bb3  = allocH((size_t)BS_ * D_);
  u16* bb4  = allocH((size_t)BS_ * D_);
  u16* bb5  = allocH((size_t)B_ * H_ * S_ * S_);
  u16* bbQK = allocH((size_t)BS_ * 2 * D_);     // qa|ka side-by-side
  u16* bbCQK= allocH((size_t)BNS_ * 2 * DS_);   // cq|ck side-by-side
  u16* cc0b = allocH((size_t)BNS_ * DS_);
  u16* ccwb = allocH((size_t)BNS_ * DS_);
  u16* sqb  = allocH((size_t)BNS_ * DS_);
  u16* tkb  = allocH((size_t)BS_ * DS_);
  u16* tvTb = allocH((size_t)DS_ * BS_);
  u16* ccnb = allocH((size_t)BNS_ * DS_);
  u16* cv2Tb= allocH((size_t)DS_ * BNS_);
  u16* csab = allocH((size_t)BNS_ * DS_);
  if (off > ws_size) return;
  (void)cvT; (void)akT; (void)avT; (void)tvTw; (void)ck2T; (void)cv2T;

  auto gemm = [&](int M, int N, int K, int z, int zdiv,
                  const u16* Ap, int lda, ll sa, ll sa2,
                  const u16* Bq, int ldb, ll sb, ll sb2,
                  float* oF, u16* oB, int ldc, ll sc, ll sc2,
                  u16* oBT, int ldt, ll st, ll st2,
                  const float* bias, const float* rsc, int rscfrom,
                  int splitcol, int act) {
    const ll b64 = (ll)(N / 64) * (M / 128) * z;
    if (N % 128 == 0 && b64 > 768 && (splitcol % 128) == 0) {
      dim3 g(N / 128, M / 128, z);
      k_gemm<128><<<g, 512, 0, stream>>>(Ap, lda, sa, sa2, Bq, ldb, sb, sb2,
          oF, oB, ldc, sc, sc2, oBT, ldt, st, st2, K, zdiv, bias, rsc, rscfrom, splitcol, act);
    } else {
      dim3 g(N / 64, M / 128, z);
      k_gemm<64><<<g, 512, 0, stream>>>(Ap, lda, sa, sa2, Bq, ldb, sb, sb2,
          oF, oB, ldc, sc, sc2, oBT, ldt, st, st2, K, zdiv, bias, rsc, rscfrom, splitcol, act);
    }
  };
  auto tcvt = [&](const float* in, u16* o, int R, int C) {
    dim3 g(C / 32, R / 32);
    k_tcvt<<<g, 256, 0, stream>>>(in, o, R, C);
  };
  auto lnorm = [&](const float* xp, const float* rp, const float* rp2, const float* rb,
                   const float* g, const float* b, float* oF, u16* oB, int rows, int cols) {
    k_layernorm<<<rows, 256, 0, stream>>>(xp, rp, rp2, rb, g, b, oF, oB, cols);
  };
  auto eg = [](int n) { return dim3((n + 255) / 256); };

  // ---- weight prep ----
  tcvt(rq_w, rqT, D_, D_);
  tcvt(ck_w, ckT, DS_, D_);
  tcvt(cv_w, cvT, DS_, D_);
  tcvt(aq_w, aqT, D_, D_);
  tcvt(ak_w, akT, D_, D_);
  tcvt(av_w, avT, D_, D_);
  tcvt(ao_w, aoT, D_, D_);
  tcvt(f1_w, f1T, D_, DFF_);
  tcvt(f2_w, f2T, DFF_, D_);
  tcvt(sq_w, sqT, DS_, DS_);
  tcvt(tk_w, tkT, D_, DS_);
  tcvt(tv_w, tvTw, D_, DS_);
  tcvt(cq_w, cqT, DS_, DS_);
  tcvt(ck2_w, ck2T, DS_, DS_);
  tcvt(cv2_w, cv2T, DS_, DS_);
  tcvt(co_w, coT, DS_, DS_);
  k_cvt<<<eg(BNS_ * DS_), 256, 0, stream>>>(cache0, cc0b, BNS_ * DS_);
  k_cat3f<<<eg(3 * D_), 256, 0, stream>>>(qkvb, aq_b, D_, ak_b, D_, av_b, D_);
  k_cat3f<<<eg(3 * DS_), 256, 0, stream>>>(cqkvb, cq_b, DS_, ck2_b, DS_, cv2_b, DS_);

  // ---- mem_read ----
  auto mem_read = [&](const float* h_f, const u16* h_b, const u16* cc_b, float* o_henh) {
    gemm(BS_, D_, D_, 1, 1, h_b, D_, 0, 0, rqT, D_, 0, 0,
         nullptr, bb2, D_, 0, 0, nullptr, 0, 0, 0,
         nullptr, nullptr, 0, D_, 0);                                               // q
    gemm(BNS_, 2 * D_, DS_, 1, 1, cc_b, DS_, 0, 0, ckT, DS_, 0, 0,
         nullptr, bb3, D_, 0, 0, bb4, BNS_, 0, 0,
         nullptr, nullptr, 0, D_, 0);                                               // k|v^T fused
    gemm(S_, NSLOT_, D_, B_, 1, bb2, D_, (ll)S_ * D_, 0,
         bb3, D_, (ll)NSLOT_ * D_, 0,
         nullptr, bb5, NSLOT_, (ll)S_ * NSLOT_, 0, nullptr, 0, 0, 0,
         nullptr, nullptr, 0, NSLOT_, 0);                                           // q k^T
    k_softmax_b16<<<B_ * S_, 256, 0, stream>>>(bb5, NSLOT_, 0.03125f);
    gemm(S_, D_, NSLOT_, B_, 1, bb5, NSLOT_, (ll)S_ * NSLOT_, 0,
         bb4, BNS_, NSLOT_, 0,
         tA, nullptr, D_, (ll)S_ * D_, 0, nullptr, 0, 0, 0,
         nullptr, nullptr, 0, D_, 0);                                               // readout
    k_gate<<<BS_ / 4, 256, 0, stream>>>(h_f, rg_w, rg_b, gate, D_);
    k_gated_add<<<eg(BS_ * D_), 256, 0, stream>>>(o_henh, h_f, tA, gate, BS_ * D_, D_);
  };

  // ---- compute_block ----
  auto compute_block = [&](const float* he, float* oF, u16* oB) {
    lnorm(he, nullptr, nullptr, nullptr, n1_g, n1_b, nullptr, bb1, BS_, D_);        // hn
    gemm(BS_, 3 * D_, D_, 1, 1, bb1, D_, 0, 0, aqT, D_, 0, 0,
         nullptr, bbQK, 2 * D_, 0, 0, bb4, BS_, 0, 0,
         qkvb, nullptr, 0, 2 * D_, 0);                                              // qkv fused (va^T->bb4)
    gemm(S_, S_, HD_, B_ * H_, H_,
         bbQK, 2 * D_, (ll)S_ * 2 * D_, HD_,
         bbQK + D_, 2 * D_, (ll)S_ * 2 * D_, HD_,
         nullptr, bb5, S_, (ll)H_ * S_ * S_, (ll)S_ * S_, nullptr, 0, 0, 0,
         nullptr, nullptr, 0, S_, 0);                                               // scores
    k_softmax_b16<<<B_ * H_ * S_, 256, 0, stream>>>(bb5, S_, 0.0625f);
    gemm(S_, HD_, S_, B_ * H_, H_,
         bb5, S_, (ll)H_ * S_ * S_, (ll)S_ * S_,
         bb4, BS_, S_, (ll)HD_ * BS_,
         nullptr, bb2, D_, (ll)S_ * D_, HD_, nullptr, 0, 0, 0,
         nullptr, nullptr, 0, HD_, 0);                                              // attnv
    gemm(BS_, D_, D_, 1, 1, bb2, D_, 0, 0, aoT, D_, 0, 0,
         tA, nullptr, D_, 0, 0, nullptr, 0, 0, 0,
         ao_b, nullptr, 0, D_, 0);                                                  // attno
    lnorm(he, tA, nullptr, nullptr, n1_g, n1_b, h2b, bb1, BS_, D_);                 // h2
    gemm(BS_, DFF_, D_, 1, 1, bb1, D_, 0, 0, f1T, D_, 0, 0,
         nullptr, bb5, DFF_, 0, 0, nullptr, 0, 0, 0,
         f1_b, nullptr, 0, DFF_, 1);                                                // f1+gelu
    gemm(BS_, D_, 2048, 2, 2, bb5, DFF_, 0, 2048, f2T, DFF_, 0, 2048,
         tA, nullptr, D_, 0, (ll)BS_ * D_, nullptr, 0, 0, 0,
         nullptr, nullptr, 0, D_, 0);                                               // f2 split-K=2 (no bias)
    lnorm(h2b, tA, tA + (ll)BS_ * D_, f2_b, n2_g, n2_b, oF, oB, BS_, D_);           // LN(h2+p0+p1+f2_b)
  };

  // ---- mem_write + cache self-attn (skipped in last iter) ----
  auto mem_write_csa = [&](const float* hc_f, const u16* hc_b,
                           const float* ccin_f, const u16* ccin_b) {
    gemm(BNS_, DS_, DS_, 1, 1, ccin_b, DS_, 0, 0, sqT, DS_, 0, 0,
         nullptr, sqb, DS_, 0, 0, nullptr, 0, 0, 0,
         nullptr, nullptr, 0, DS_, 0);                                              // sq
    k_gate<<<BS_ / 4, 256, 0, stream>>>(hc_f, wg_w, wg_b, gate, D_);
    gemm(BS_, 2 * DS_, D_, 1, 1, hc_b, D_, 0, 0, tkT, D_, 0, 0,
         nullptr, tkb, DS_, 0, 0, tvTb, BS_, 0, 0,
         nullptr, gate, DS_, DS_, 0);                                               // tk | (gate*tv)^T
    gemm(NSLOT_, S_, DS_, B_, 1, sqb, DS_, (ll)NSLOT_ * DS_, 0,
         tkb, DS_, (ll)S_ * DS_, 0,
         nullptr, bb5, S_, (ll)NSLOT_ * S_, 0, nullptr, 0, 0, 0,
         nullptr, nullptr, 0, S_, 0);                                               // slot scores
    k_softmax_b16<<<B_ * NSLOT_, 256, 0, stream>>>(bb5, S_, 0.05590169943749474f);
    gemm(NSLOT_, DS_, S_, B_, 1, bb5, S_, (ll)NSLOT_ * S_, 0,
         tvTb, BS_, S_, 0,
         updf, nullptr, DS_, (ll)NSLOT_ * DS_, 0, nullptr, 0, 0, 0,
         nullptr, nullptr, 0, DS_, 0);                                              // upd
    k_add2<<<eg(BNS_ * DS_), 256, 0, stream>>>(ccnf, ccnb, ccin_f, updf, BNS_ * DS_);
    gemm(BNS_, 3 * DS_, DS_, 1, 1, ccnb, DS_, 0, 0, cqT, DS_, 0, 0,
         nullptr, bbCQK, 2 * DS_, 0, 0, cv2Tb, BNS_, 0, 0,
         cqkvb, nullptr, 0, 2 * DS_, 0);                                            // cq|ck|cv^T fused
    gemm(NSLOT_, NSLOT_, CHD_, B_ * CH_, CH_,
         bbCQK, 2 * DS_, (ll)NSLOT_ * 2 * DS_, CHD_,
         bbCQK + DS_, 2 * DS_, (ll)NSLOT_ * 2 * DS_, CHD_,
         nullptr, bb5, NSLOT_, (ll)CH_ * NSLOT_ * NSLOT_, (ll)NSLOT_ * NSLOT_,
         nullptr, 0, 0, 0, nullptr, nullptr, 0, NSLOT_, 0);                         // csa scores
    k_softmax_b16<<<B_ * CH_ * NSLOT_, 256, 0, stream>>>(bb5, NSLOT_, 0.125f);
    gemm(NSLOT_, CHD_, NSLOT_, B_ * CH_, CH_,
         bb5, NSLOT_, (ll)CH_ * NSLOT_ * NSLOT_, (ll)NSLOT_ * NSLOT_,
         cv2Tb, BNS_, NSLOT_, (ll)CHD_ * BNS_,
         nullptr, csab, DS_, (ll)NSLOT_ * DS_, CHD_, nullptr, 0, 0, 0,
         nullptr, nullptr, 0, CHD_, 0);                                             // csa pv
    gemm(BNS_, DS_, DS_, 1, 1, csab, DS_, 0, 0, coT, DS_, 0, 0,
         coo, nullptr, DS_, 0, 0, nullptr, 0, 0, 0,
         co_b, nullptr, 0, DS_, 0);                                                 // co
    lnorm(ccnf, coo, nullptr, nullptr, cn_g, cn_b, ccwf, ccwb, BNS_, DS_);
  };

  // ================= iteration 0 =================
  k_combine2<<<eg(BS_ * D_), 256, 0, stream>>>(hbuf, bb1, x, 1.0f, nullptr, iter_emb, BS_ * D_, D_ - 1);
  mem_read(hbuf, bb1, cc0b, henh);
  compute_block(henh, hcomp, bb3);
  mem_write_csa(hcomp, bb3, cache0, cc0b);

  // ================= iteration 1 (last: cache update dead, skipped) =================
  k_combine2<<<eg(BS_ * D_), 256, 0, stream>>>(hbuf, bb1, hcomp, 2.0f, x, iter_emb + D_, BS_ * D_, D_ - 1);
  mem_read(hbuf, bb1, ccwb, henh);
  compute_block(henh, out, nullptr);
}

// Round 10
// 553.007 us; speedup vs baseline: 1.5746x; 1.0457x over previous
//
#include <hip/hip_runtime.h>
#include <cstdint>

// ---------------- problem constants ----------------
constexpr int B_ = 2, S_ = 1024, D_ = 1024, DS_ = 320, NSLOT_ = 512;
constexpr int H_ = 4, CH_ = 5, DFF_ = 4096;
constexpr int HD_ = D_ / H_;      // 256
constexpr int CHD_ = DS_ / CH_;   // 64
constexpr int BS_ = B_ * S_;      // 2048
constexpr int BNS_ = B_ * NSLOT_; // 1024

typedef unsigned short u16;
typedef __attribute__((ext_vector_type(8))) short bf16x8;
typedef __attribute__((ext_vector_type(4))) float f32x4;
typedef __attribute__((ext_vector_type(4))) u16 u16x4;
typedef long long ll;

__device__ __forceinline__ u16 f2bf(float f) {
  unsigned u = __float_as_uint(f);
  return (u16)((u + 0x7FFFu + ((u >> 16) & 1u)) >> 16);  // RNE
}
__device__ __forceinline__ float bf2f(u16 h) { return __uint_as_float((unsigned)h << 16); }

__device__ __forceinline__ void gload16(const void* g, void* l) {
  __builtin_amdgcn_global_load_lds((const __attribute__((address_space(1))) void*)g,
                                   (__attribute__((address_space(3))) void*)l, 16, 0, 0);
}

// ---------------- bf16 MFMA GEMM: C[m,n] = sum_k A[m,k]*B[n,k] ----------------
// r6-proven geometry: BM=128, BK=64, 512 thr, double-buffered, XOR-swizzled
// LDS (0 bank conflicts, verified r3/r6).
//   BN=128: waves 4x2, per-wave 32x64, LDS 64KB (2 blocks/CU)
//   BN=64 : waves 8x1, per-wave 16x64, LDS 48KB (3 blocks/CU)
// NEW (r10): SINGLE barrier per K-step. Order per iter:
//   vmcnt(0)  [drain stage issued last iter; had a full body in flight]
//   barrier   [implies all waves' prev-buffer ds_reads done (trailing lgkm(0))]
//   stage(next buf)  [safe: overwrites buffer whose readers all passed barrier]
//   ds_read cur; MFMA; lgkmcnt(0)
// Column-split epilogue: cn < splitcol -> outF/outB normal; else transposed.
template<int BN>
__global__ __launch_bounds__(512, 4)
void k_gemm(const u16* __restrict__ A, int lda, ll sA, ll sA2,
            const u16* __restrict__ Bp, int ldb, ll sB, ll sB2,
            float* __restrict__ outF, u16* __restrict__ outB,
            int ldc, ll sC, ll sC2,
            u16* __restrict__ outBT, int ldt, ll sT, ll sT2,
            int K, int zdiv, const float* __restrict__ bias,
            const float* __restrict__ rowscale, int rscfrom,
            int splitcol, int act)
{
  constexpr int BM = 128;
  constexpr int MI = (BN == 128) ? 2 : 1;
  constexpr int NI = 4;
  constexpr int WROWS = MI * 16;
  constexpr int ABYT = BM * 128;            // 16 KB
  constexpr int BBYT = BN * 128;
  constexpr int BUF = ABYT + BBYT;
  const int z = blockIdx.z, zb = z / zdiv, zr = z - zb * zdiv;
  A  += (ll)zb * sA + (ll)zr * sA2;
  Bp += (ll)zb * sB + (ll)zr * sB2;
  const ll cof = (ll)zb * sC + (ll)zr * sC2;
  const ll tof = (ll)zb * sT + (ll)zr * sT2;
  const int bm = blockIdx.y * BM, bn = blockIdx.x * BN;
  __shared__ __align__(16) char lds[2 * BUF];
  const int tid = threadIdx.x;
  const int lane = tid & 63, wid = tid >> 6;
  const int wm = (BN == 128) ? (wid >> 1) : wid;
  const int wn = (BN == 128) ? (wid & 1) : 0;
  const int rowb = wm * WROWS, colb = wn * 64;

  f32x4 acc[MI][NI];
  const f32x4 fz = {0.f, 0.f, 0.f, 0.f};
  #pragma unroll
  for (int i = 0; i < MI; ++i)
    #pragma unroll
    for (int j = 0; j < NI; ++j) acc[i][j] = fz;

  // staging: thread t -> row t>>3, granule t&7; source granule ^= row&7;
  // LDS dest linear (wave-uniform base + lane*16).
  const int trow = tid >> 3;
  const int tg   = ((tid & 7) ^ (trow & 7)) * 8;
  const u16* gA  = A + (ll)(bm + trow) * lda + tg;
  const u16* gA2 = gA + (ll)64 * lda;
  const u16* gB  = Bp + (ll)(bn + trow) * ldb + tg;
  const u16* gB2 = gB + (ll)64 * ldb;       // only for BN==128

  // fragment read offsets: row' = base + i*16 + r; granule (4s+q) ^ (r&7)
  const int r = lane & 15, q = lane >> 4;
  const int c7 = r & 7;
  const int gs0 = ((q) ^ c7) << 4;
  const int gs1 = ((4 + q) ^ c7) << 4;
  int aoff[MI], boff[NI];
  #pragma unroll
  for (int i = 0; i < MI; ++i) aoff[i] = (rowb + i * 16 + r) * 128;
  #pragma unroll
  for (int j = 0; j < NI; ++j) boff[j] = (colb + j * 16 + r) * 128;

  auto stage = [&](int buf, int it) {
    char* la = lds + buf * BUF + wid * 1024;
    char* lb = la + ABYT;
    const int ko = it << 6;
    gload16(gA + ko, la);
    gload16(gA2 + ko, la + 8192);
    gload16(gB + ko, lb);
    if constexpr (BN == 128) gload16(gB2 + ko, lb + 8192);
  };

  const int nsteps = K >> 6;
  stage(0, 0);
  int bufp = 0;
  for (int it = 0; it < nsteps; ++it) {
    asm volatile("s_waitcnt vmcnt(0)" ::: "memory");   // drain stage from last iter
    __builtin_amdgcn_s_barrier();                      // single barrier per step
    __builtin_amdgcn_sched_barrier(0);
    if (it + 1 < nsteps) stage(bufp ^ 1, it + 1);      // safe: readers passed barrier
    const char* pa = lds + bufp * BUF;
    const char* pb = pa + ABYT;
    #pragma unroll
    for (int s = 0; s < 2; ++s) {
      const int gso = s ? gs1 : gs0;
      bf16x8 af[MI], bv[NI];
      #pragma unroll
      for (int i = 0; i < MI; ++i) af[i] = *(const bf16x8*)(pa + aoff[i] + gso);
      #pragma unroll
      for (int j = 0; j < NI; ++j) bv[j] = *(const bf16x8*)(pb + boff[j] + gso);
      #pragma unroll
      for (int i = 0; i < MI; ++i)
        #pragma unroll
        for (int j = 0; j < NI; ++j)
          acc[i][j] = __builtin_amdgcn_mfma_f32_16x16x32_bf16(af[i], bv[j], acc[i][j], 0, 0, 0);
    }
    asm volatile("s_waitcnt lgkmcnt(0)" ::: "memory"); // reads of buf[bufp] done
    __builtin_amdgcn_sched_barrier(0);
    bufp ^= 1;
  }

  const int fr = lane & 15, fq = lane >> 4;
  #pragma unroll
  for (int i = 0; i < MI; ++i) {
    const int r0 = bm + rowb + i * 16 + fq * 4;
    #pragma unroll
    for (int j = 0; j < NI; ++j) {
      const int cn = bn + colb + j * 16 + fr;
      const float bvv = bias ? bias[cn] : 0.f;
      const bool doRs = rowscale && (cn >= rscfrom);
      float vv[4];
      #pragma unroll
      for (int t = 0; t < 4; ++t) {
        float v = acc[i][j][t] + bvv;
        if (doRs) v *= rowscale[r0 + t];
        if (act) v = 0.5f * v * (1.f + tanhf(0.7978845608028654f * (v + 0.044715f * v * v * v)));
        vv[t] = v;
      }
      if (cn < splitcol) {
        if (outF) {
          #pragma unroll
          for (int t = 0; t < 4; ++t) outF[cof + (ll)(r0 + t) * ldc + cn] = vv[t];
        }
        if (outB) {
          #pragma unroll
          for (int t = 0; t < 4; ++t) outB[cof + (ll)(r0 + t) * ldc + cn] = f2bf(vv[t]);
        }
      } else {
        u16x4 pk = {f2bf(vv[0]), f2bf(vv[1]), f2bf(vv[2]), f2bf(vv[3])};
        *(u16x4*)(outBT + tof + (ll)(cn - splitcol) * ldt + r0) = pk;
      }
    }
  }
}

// ---------------- consolidated weight prep: 16 transposes in ONE dispatch ----------------
struct PrepTable {
  const float* src[16];
  u16* dst[16];
  int R[16];
  int C[16];
  int off[17];
};

__global__ __launch_bounds__(256)
void k_prep_all(PrepTable T)
{
  __shared__ float t[32][33];
  const int b = blockIdx.x;
  int w = 0;
  #pragma unroll
  for (int i = 1; i < 16; ++i) if (b >= T.off[i]) w = i;
  const int lb = b - T.off[w];
  const int tilesC = T.C[w] >> 5;
  const int by = (lb / tilesC) << 5;
  const int bx = (lb - (lb / tilesC) * tilesC) << 5;
  const float* in = T.src[w];
  u16* out = T.dst[w];
  const int R = T.R[w], C = T.C[w];
  const int tx = threadIdx.x & 31, ty = threadIdx.x >> 5;
  #pragma unroll
  for (int i = 0; i < 32; i += 8)
    t[ty + i][tx] = in[(ll)(by + ty + i) * C + bx + tx];
  __syncthreads();
  #pragma unroll
  for (int i = 0; i < 32; i += 8)
    out[(ll)(bx + ty + i) * R + by + tx] = f2bf(t[tx][ty + i]);
}

__global__ __launch_bounds__(256)
void k_cvt(const float* __restrict__ in, u16* __restrict__ out, int n)
{
  int i = blockIdx.x * 256 + threadIdx.x;
  if (i < n) out[i] = f2bf(in[i]);
}

// concat 3 fp32 vectors
__global__ __launch_bounds__(256)
void k_cat3f(float* __restrict__ dst, const float* __restrict__ a, int na,
             const float* __restrict__ b, int nb, const float* __restrict__ c, int nc)
{
  int i = blockIdx.x * 256 + threadIdx.x;
  if (i < na) dst[i] = a[i];
  else if (i < na + nb) dst[i] = b[i - na];
  else if (i < na + nb + nc) dst[i] = c[i - na - nb];
}

// ---------------- row softmax on bf16 in place (cols <= 1024) ----------------
__global__ __launch_bounds__(256)
void k_softmax_b16(u16* __restrict__ x, int cols, float scale)
{
  u16* p = x + (ll)blockIdx.x * cols;
  const int tid = threadIdx.x;
  __shared__ float red[256];
  float v[4];
  float m = -1e30f;
  #pragma unroll
  for (int i = 0; i < 4; ++i) {
    const int c = tid + (i << 8);
    v[i] = (c < cols) ? bf2f(p[c]) * scale : -1e30f;
    m = fmaxf(m, v[i]);
  }
  red[tid] = m; __syncthreads();
  for (int s = 128; s > 0; s >>= 1) { if (tid < s) red[tid] = fmaxf(red[tid], red[tid + s]); __syncthreads(); }
  m = red[0]; __syncthreads();
  float sum = 0.f;
  #pragma unroll
  for (int i = 0; i < 4; ++i) { v[i] = expf(v[i] - m); sum += v[i]; }
  red[tid] = sum; __syncthreads();
  for (int s = 128; s > 0; s >>= 1) { if (tid < s) red[tid] += red[tid + s]; __syncthreads(); }
  const float inv = 1.f / red[0];
  #pragma unroll
  for (int i = 0; i < 4; ++i) {
    const int c = tid + (i << 8);
    if (c < cols) p[c] = f2bf(v[i] * inv);
  }
}

// ---------------- layernorm: LN(x [+res][+res2][+rbias])*g + b ----------------
__global__ __launch_bounds__(256)
void k_layernorm(const float* __restrict__ x, const float* __restrict__ res,
                 const float* __restrict__ res2, const float* __restrict__ rbias,
                 const float* __restrict__ g, const float* __restrict__ b,
                 float* __restrict__ outF, u16* __restrict__ outB, int cols)
{
  const ll ro = (ll)blockIdx.x * cols;
  const float* px = x + ro;
  const float* pr = res ? res + ro : nullptr;
  const float* p2 = res2 ? res2 + ro : nullptr;
  __shared__ float red[256];
  const int tid = threadIdx.x;
  auto val = [&](int c) {
    float v = px[c];
    if (pr) v += pr[c];
    if (p2) v += p2[c];
    if (rbias) v += rbias[c];
    return v;
  };
  float s = 0.f;
  for (int c = tid; c < cols; c += 256) s += val(c);
  red[tid] = s; __syncthreads();
  for (int t = 128; t > 0; t >>= 1) { if (tid < t) red[tid] += red[tid + t]; __syncthreads(); }
  const float mean = red[0] / cols; __syncthreads();
  float s2 = 0.f;
  for (int c = tid; c < cols; c += 256) { float v = val(c) - mean; s2 += v * v; }
  red[tid] = s2; __syncthreads();
  for (int t = 128; t > 0; t >>= 1) { if (tid < t) red[tid] += red[tid + t]; __syncthreads(); }
  const float inv = rsqrtf(red[0] / cols + 1e-5f);
  for (int c = tid; c < cols; c += 256) {
    float v = (val(c) - mean) * inv * g[c] + b[c];
    if (outF) outF[ro + c] = v;
    if (outB) outB[ro + c] = f2bf(v);
  }
}

// ---------------- fused gate + gated add: out = h + sigmoid(h.w+b0)*r, per row ----------------
__global__ __launch_bounds__(256)
void k_gate_add(float* __restrict__ out, const float* __restrict__ h,
                const float* __restrict__ r, const float* __restrict__ w,
                const float* __restrict__ b0, int cols)
{
  const ll ro = (ll)blockIdx.x * cols;
  const float* ph = h + ro;
  const float* pr = r + ro;
  __shared__ float red[256];
  const int tid = threadIdx.x;
  float s = 0.f;
  for (int c = tid; c < cols; c += 256) s += ph[c] * w[c];
  red[tid] = s; __syncthreads();
  for (int t = 128; t > 0; t >>= 1) { if (tid < t) red[tid] += red[tid + t]; __syncthreads(); }
  const float g = 1.0f / (1.0f + expf(-(red[0] + b0[0])));
  for (int c = tid; c < cols; c += 256) out[ro + c] = ph[c] + g * pr[c];
}

// ---------------- gate[row] = sigmoid(dot(x[row], w) + b0), 1 wave / row ----------------
__global__ __launch_bounds__(256)
void k_gate(const float* __restrict__ x, const float* __restrict__ w,
            const float* __restrict__ b0, float* __restrict__ out, int cols)
{
  const int lane = threadIdx.x & 63;
  const int wv = threadIdx.x >> 6;
  const ll row = (ll)blockIdx.x * 4 + wv;
  const float* p = x + row * cols;
  float s = 0.f;
  for (int c = lane; c < cols; c += 64) s += p[c] * w[c];
  #pragma unroll
  for (int off = 32; off > 0; off >>= 1) s += __shfl_down(s, off);
  if (lane == 0) out[row] = 1.0f / (1.0f + expf(-(s + b0[0])));
}

// ---------------- elementwise ----------------
__global__ __launch_bounds__(256)
void k_combine2(float* __restrict__ oF, u16* __restrict__ oB,
                const float* __restrict__ a, float sa, const float* __restrict__ b,
                const float* __restrict__ emb, int n, int Dm1)
{
  int i = blockIdx.x * 256 + threadIdx.x;
  if (i >= n) return;
  float v = sa * a[i];
  if (b) v += b[i];
  v += emb[i & Dm1];
  oF[i] = v; oB[i] = f2bf(v);
}

__global__ __launch_bounds__(256)
void k_add2(float* __restrict__ oF, u16* __restrict__ oB,
            const float* __restrict__ a, const float* __restrict__ b, int n)
{
  int i = blockIdx.x * 256 + threadIdx.x;
  if (i >= n) return;
  float v = a[i] + b[i];
  oF[i] = v; oB[i] = f2bf(v);
}

// ---------------- host ----------------
extern "C" void kernel_launch(void* const* d_in, const int* in_sizes, int n_in,
                              void* d_out, int out_size, void* d_ws, size_t ws_size,
                              hipStream_t stream)
{
  (void)in_sizes; (void)n_in; (void)out_size;
  const float* x        = (const float*)d_in[0];
  const float* cache0   = (const float*)d_in[1];
  const float* iter_emb = (const float*)d_in[2];
  const float* rq_w     = (const float*)d_in[3];
  const float* rg_w     = (const float*)d_in[4];
  const float* rg_b     = (const float*)d_in[5];
  const float* ck_w     = (const float*)d_in[6];
  const float* cv_w     = (const float*)d_in[7];
  const float* aq_w     = (const float*)d_in[8];
  const float* ak_w     = (const float*)d_in[9];
  const float* av_w     = (const float*)d_in[10];
  const float* ao_w     = (const float*)d_in[11];
  const float* aq_b     = (const float*)d_in[12];
  const float* ak_b     = (const float*)d_in[13];
  const float* av_b     = (const float*)d_in[14];
  const float* ao_b     = (const float*)d_in[15];
  const float* f1_w     = (const float*)d_in[16];
  const float* f1_b     = (const float*)d_in[17];
  const float* f2_w     = (const float*)d_in[18];
  const float* f2_b     = (const float*)d_in[19];
  const float* n1_g     = (const float*)d_in[20];
  const float* n1_b     = (const float*)d_in[21];
  const float* n2_g     = (const float*)d_in[22];
  const float* n2_b     = (const float*)d_in[23];
  const float* sq_w     = (const float*)d_in[24];
  const float* tk_w     = (const float*)d_in[25];
  const float* tv_w     = (const float*)d_in[26];
  const float* wg_w     = (const float*)d_in[27];
  const float* wg_b     = (const float*)d_in[28];
  const float* cq_w     = (const float*)d_in[29];
  const float* ck2_w    = (const float*)d_in[30];
  const float* cv2_w    = (const float*)d_in[31];
  const float* co_w     = (const float*)d_in[32];
  const float* cq_b     = (const float*)d_in[33];
  const float* ck2_b    = (const float*)d_in[34];
  const float* cv2_b    = (const float*)d_in[35];
  const float* co_b     = (const float*)d_in[36];
  const float* cn_g     = (const float*)d_in[37];
  const float* cn_b     = (const float*)d_in[38];
  // d_in[39] = max_iterations (fixed 2; schedule hardcoded for graph capture)

  float* out = (float*)d_out;

  // -------- workspace carve --------
  size_t off = 0;
  char* base = (char*)d_ws;
  auto allocF = [&](size_t n) { float* p = (float*)(base + off); off += n * 4; off = (off + 255) & ~(size_t)255; return p; };
  auto allocH = [&](size_t n) { u16* p = (u16*)(base + off); off += n * 2; off = (off + 255) & ~(size_t)255; return p; };

  float* hbuf  = allocF((size_t)BS_ * D_);
  float* henh  = allocF((size_t)BS_ * D_);
  float* hcomp = allocF((size_t)BS_ * D_);
  float* h2b   = allocF((size_t)BS_ * D_);
  float* tA    = allocF((size_t)2 * BS_ * D_);   // fp32 temp + f2 split-K partials
  float* gate  = allocF((size_t)BS_);
  float* ccnf  = allocF((size_t)BNS_ * DS_);
  float* updf  = allocF((size_t)BNS_ * DS_);
  float* coo   = allocF((size_t)BNS_ * DS_);
  float* ccwf  = allocF((size_t)BNS_ * DS_);
  float* qkvb  = allocF(3 * D_);
  float* cqkvb = allocF(3 * DS_);
  // bf16 weights [N][K]; stacked groups MUST stay adjacent (fused GEMMs):
  u16* rqT  = allocH((size_t)D_ * D_);
  u16* ckT  = allocH((size_t)D_ * DS_);   // kvT = ckT (ck|cv stacked, 2048x320)
  u16* cvT  = allocH((size_t)D_ * DS_);
  u16* aqT  = allocH((size_t)D_ * D_);    // qkvT = aqT (aq|ak|av stacked, 3072x1024)
  u16* akT  = allocH((size_t)D_ * D_);
  u16* avT  = allocH((size_t)D_ * D_);
  u16* aoT  = allocH((size_t)D_ * D_);
  u16* f1T  = allocH((size_t)DFF_ * D_);
  u16* f2T  = allocH((size_t)D_ * DFF_);
  u16* sqT  = allocH((size_t)DS_ * DS_);
  u16* tkT  = allocH((size_t)DS_ * D_);   // tktvT = tkT (tk|tv stacked, 640x1024)
  u16* tvTw = allocH((size_t)DS_ * D_);
  u16* cqT  = allocH((size_t)DS_ * DS_);  // cqkvT = cqT (cq|ck|cv stacked, 960x320)
  u16* ck2T = allocH((size_t)DS_ * DS_);
  u16* cv2T = allocH((size_t)DS_ * DS_);
  u16* coT  = allocH((size_t)DS_ * DS_);
  // bf16 activations
  u16* bb1  = allocH((size_t)BS_ * D_);
  u16* bb2  = allocH((size_t)BS_ * D_);
  u16* bb3  = allocH((size_t)BS_ * D_);
  u16* bb4  = allocH((size_t)BS_ * D_);
  u16* bb5  = allocH((size_t)B_ * H_ * S_ * S_);
  u16* bbQK = allocH((size_t)BS_ * 2 * D_);     // qa|ka side-by-side
  u16* bbCQK= allocH((size_t)BNS_ * 2 * DS_);   // cq|ck side-by-side
  u16* cc0b = allocH((size_t)BNS_ * DS_);
  u16* ccwb = allocH((size_t)BNS_ * DS_);
  u16* sqb  = allocH((size_t)BNS_ * DS_);
  u16* tkb  = allocH((size_t)BS_ * DS_);
  u16* tvTb = allocH((size_t)DS_ * BS_);
  u16* ccnb = allocH((size_t)BNS_ * DS_);
  u16* cv2Tb= allocH((size_t)DS_ * BNS_);
  u16* csab = allocH((size_t)BNS_ * DS_);
  if (off > ws_size) return;
  (void)cvT; (void)akT; (void)avT; (void)tvTw; (void)ck2T; (void)cv2T;

  auto gemm = [&](int M, int N, int K, int z, int zdiv,
                  const u16* Ap, int lda, ll sa, ll sa2,
                  const u16* Bq, int ldb, ll sb, ll sb2,
                  float* oF, u16* oB, int ldc, ll sc, ll sc2,
                  u16* oBT, int ldt, ll st, ll st2,
                  const float* bias, const float* rsc, int rscfrom,
                  int splitcol, int act) {
    const ll b64 = (ll)(N / 64) * (M / 128) * z;
    if (N % 128 == 0 && b64 > 768 && (splitcol % 128) == 0) {
      dim3 g(N / 128, M / 128, z);
      k_gemm<128><<<g, 512, 0, stream>>>(Ap, lda, sa, sa2, Bq, ldb, sb, sb2,
          oF, oB, ldc, sc, sc2, oBT, ldt, st, st2, K, zdiv, bias, rsc, rscfrom, splitcol, act);
    } else {
      dim3 g(N / 64, M / 128, z);
      k_gemm<64><<<g, 512, 0, stream>>>(Ap, lda, sa, sa2, Bq, ldb, sb, sb2,
          oF, oB, ldc, sc, sc2, oBT, ldt, st, st2, K, zdiv, bias, rsc, rscfrom, splitcol, act);
    }
  };
  auto lnorm = [&](const float* xp, const float* rp, const float* rp2, const float* rb,
                   const float* g, const float* b, float* oF, u16* oB, int rows, int cols) {
    k_layernorm<<<rows, 256, 0, stream>>>(xp, rp, rp2, rb, g, b, oF, oB, cols);
  };
  auto eg = [](int n) { return dim3((n + 255) / 256); };

  // ---- weight prep: ONE dispatch for all 16 transposes ----
  {
    PrepTable T;
    const float* srcs[16] = {rq_w, ck_w, cv_w, aq_w, ak_w, av_w, ao_w, f1_w,
                             f2_w, sq_w, tk_w, tv_w, cq_w, ck2_w, cv2_w, co_w};
    u16* dsts[16] = {rqT, ckT, cvT, aqT, akT, avT, aoT, f1T,
                     f2T, sqT, tkT, tvTw, cqT, ck2T, cv2T, coT};
    const int Rs[16] = {D_, DS_, DS_, D_, D_, D_, D_, D_, DFF_, DS_, D_, D_, DS_, DS_, DS_, DS_};
    const int Cs[16] = {D_, D_, D_, D_, D_, D_, D_, DFF_, D_, DS_, DS_, DS_, DS_, DS_, DS_, DS_};
    int acc0 = 0;
    for (int i = 0; i < 16; ++i) {
      T.src[i] = srcs[i]; T.dst[i] = dsts[i]; T.R[i] = Rs[i]; T.C[i] = Cs[i];
      T.off[i] = acc0;
      acc0 += (Rs[i] >> 5) * (Cs[i] >> 5);
    }
    T.off[16] = acc0;
    k_prep_all<<<acc0, 256, 0, stream>>>(T);
  }
  k_cvt<<<eg(BNS_ * DS_), 256, 0, stream>>>(cache0, cc0b, BNS_ * DS_);
  k_cat3f<<<eg(3 * D_), 256, 0, stream>>>(qkvb, aq_b, D_, ak_b, D_, av_b, D_);
  k_cat3f<<<eg(3 * DS_), 256, 0, stream>>>(cqkvb, cq_b, DS_, ck2_b, DS_, cv2_b, DS_);

  // ---- mem_read ----
  auto mem_read = [&](const float* h_f, const u16* h_b, const u16* cc_b, float* o_henh) {
    gemm(BS_, D_, D_, 1, 1, h_b, D_, 0, 0, rqT, D_, 0, 0,
         nullptr, bb2, D_, 0, 0, nullptr, 0, 0, 0,
         nullptr, nullptr, 0, D_, 0);                                               // q
    gemm(BNS_, 2 * D_, DS_, 1, 1, cc_b, DS_, 0, 0, ckT, DS_, 0, 0,
         nullptr, bb3, D_, 0, 0, bb4, BNS_, 0, 0,
         nullptr, nullptr, 0, D_, 0);                                               // k|v^T fused
    gemm(S_, NSLOT_, D_, B_, 1, bb2, D_, (ll)S_ * D_, 0,
         bb3, D_, (ll)NSLOT_ * D_, 0,
         nullptr, bb5, NSLOT_, (ll)S_ * NSLOT_, 0, nullptr, 0, 0, 0,
         nullptr, nullptr, 0, NSLOT_, 0);                                           // q k^T
    k_softmax_b16<<<B_ * S_, 256, 0, stream>>>(bb5, NSLOT_, 0.03125f);
    gemm(S_, D_, NSLOT_, B_, 1, bb5, NSLOT_, (ll)S_ * NSLOT_, 0,
         bb4, BNS_, NSLOT_, 0,
         tA, nullptr, D_, (ll)S_ * D_, 0, nullptr, 0, 0, 0,
         nullptr, nullptr, 0, D_, 0);                                               // readout
    k_gate_add<<<BS_, 256, 0, stream>>>(o_henh, h_f, tA, rg_w, rg_b, D_);           // fused gate+add
  };

  // ---- compute_block ----
  auto compute_block = [&](const float* he, float* oF, u16* oB) {
    lnorm(he, nullptr, nullptr, nullptr, n1_g, n1_b, nullptr, bb1, BS_, D_);        // hn
    gemm(BS_, 3 * D_, D_, 1, 1, bb1, D_, 0, 0, aqT, D_, 0, 0,
         nullptr, bbQK, 2 * D_, 0, 0, bb4, BS_, 0, 0,
         qkvb, nullptr, 0, 2 * D_, 0);                                              // qkv fused (va^T->bb4)
    gemm(S_, S_, HD_, B_ * H_, H_,
         bbQK, 2 * D_, (ll)S_ * 2 * D_, HD_,
         bbQK + D_, 2 * D_, (ll)S_ * 2 * D_, HD_,
         nullptr, bb5, S_, (ll)H_ * S_ * S_, (ll)S_ * S_, nullptr, 0, 0, 0,
         nullptr, nullptr, 0, S_, 0);                                               // scores
    k_softmax_b16<<<B_ * H_ * S_, 256, 0, stream>>>(bb5, S_, 0.0625f);
    gemm(S_, HD_, S_, B_ * H_, H_,
         bb5, S_, (ll)H_ * S_ * S_, (ll)S_ * S_,
         bb4, BS_, S_, (ll)HD_ * BS_,
         nullptr, bb2, D_, (ll)S_ * D_, HD_, nullptr, 0, 0, 0,
         nullptr, nullptr, 0, HD_, 0);                                              // attnv
    gemm(BS_, D_, D_, 1, 1, bb2, D_, 0, 0, aoT, D_, 0, 0,
         tA, nullptr, D_, 0, 0, nullptr, 0, 0, 0,
         ao_b, nullptr, 0, D_, 0);                                                  // attno
    lnorm(he, tA, nullptr, nullptr, n1_g, n1_b, h2b, bb1, BS_, D_);                 // h2
    gemm(BS_, DFF_, D_, 1, 1, bb1, D_, 0, 0, f1T, D_, 0, 0,
         nullptr, bb5, DFF_, 0, 0, nullptr, 0, 0, 0,
         f1_b, nullptr, 0, DFF_, 1);                                                // f1+gelu
    gemm(BS_, D_, 2048, 2, 2, bb5, DFF_, 0, 2048, f2T, DFF_, 0, 2048,
         tA, nullptr, D_, 0, (ll)BS_ * D_, nullptr, 0, 0, 0,
         nullptr, nullptr, 0, D_, 0);                                               // f2 split-K=2 (no bias)
    lnorm(h2b, tA, tA + (ll)BS_ * D_, f2_b, n2_g, n2_b, oF, oB, BS_, D_);           // LN(h2+p0+p1+f2_b)
  };

  // ---- mem_write + cache self-attn (skipped in last iter) ----
  auto mem_write_csa = [&](const float* hc_f, const u16* hc_b,
                           const float* ccin_f, const u16* ccin_b) {
    gemm(BNS_, DS_, DS_, 1, 1, ccin_b, DS_, 0, 0, sqT, DS_, 0, 0,
         nullptr, sqb, DS_, 0, 0, nullptr, 0, 0, 0,
         nullptr, nullptr, 0, DS_, 0);                                              // sq
    k_gate<<<BS_ / 4, 256, 0, stream>>>(hc_f, wg_w, wg_b, gate, D_);
    gemm(BS_, 2 * DS_, D_, 1, 1, hc_b, D_, 0, 0, tkT, D_, 0, 0,
         nullptr, tkb, DS_, 0, 0, tvTb, BS_, 0, 0,
         nullptr, gate, DS_, DS_, 0);                                               // tk | (gate*tv)^T
    gemm(NSLOT_, S_, DS_, B_, 1, sqb, DS_, (ll)NSLOT_ * DS_, 0,
         tkb, DS_, (ll)S_ * DS_, 0,
         nullptr, bb5, S_, (ll)NSLOT_ * S_, 0, nullptr, 0, 0, 0,
         nullptr, nullptr, 0, S_, 0);                                               // slot scores
    k_softmax_b16<<<B_ * NSLOT_, 256, 0, stream>>>(bb5, S_, 0.05590169943749474f);
    gemm(NSLOT_, DS_, S_, B_, 1, bb5, S_, (ll)NSLOT_ * S_, 0,
         tvTb, BS_, S_, 0,
         updf, nullptr, DS_, (ll)NSLOT_ * DS_, 0, nullptr, 0, 0, 0,
         nullptr, nullptr, 0, DS_, 0);                                              // upd
    k_add2<<<eg(BNS_ * DS_), 256, 0, stream>>>(ccnf, ccnb, ccin_f, updf, BNS_ * DS_);
    gemm(BNS_, 3 * DS_, DS_, 1, 1, ccnb, DS_, 0, 0, cqT, DS_, 0, 0,
         nullptr, bbCQK, 2 * DS_, 0, 0, cv2Tb, BNS_, 0, 0,
         cqkvb, nullptr, 0, 2 * DS_, 0);                                            // cq|ck|cv^T fused
    gemm(NSLOT_, NSLOT_, CHD_, B_ * CH_, CH_,
         bbCQK, 2 * DS_, (ll)NSLOT_ * 2 * DS_, CHD_,
         bbCQK + DS_, 2 * DS_, (ll)NSLOT_ * 2 * DS_, CHD_,
         nullptr, bb5, NSLOT_, (ll)CH_ * NSLOT_ * NSLOT_, (ll)NSLOT_ * NSLOT_,
         nullptr, 0, 0, 0, nullptr, nullptr, 0, NSLOT_, 0);                         // csa scores
    k_softmax_b16<<<B_ * CH_ * NSLOT_, 256, 0, stream>>>(bb5, NSLOT_, 0.125f);
    gemm(NSLOT_, CHD_, NSLOT_, B_ * CH_, CH_,
         bb5, NSLOT_, (ll)CH_ * NSLOT_ * NSLOT_, (ll)NSLOT_ * NSLOT_,
         cv2Tb, BNS_, NSLOT_, (ll)CHD_ * BNS_,
         nullptr, csab, DS_, (ll)NSLOT_ * DS_, CHD_, nullptr, 0, 0, 0,
         nullptr, nullptr, 0, CHD_, 0);                                             // csa pv
    gemm(BNS_, DS_, DS_, 1, 1, csab, DS_, 0, 0, coT, DS_, 0, 0,
         coo, nullptr, DS_, 0, 0, nullptr, 0, 0, 0,
         co_b, nullptr, 0, DS_, 0);                                                 // co
    lnorm(ccnf, coo, nullptr, nullptr, cn_g, cn_b, ccwf, ccwb, BNS_, DS_);
  };

  // ================= iteration 0 =================
  k_combine2<<<eg(BS_ * D_), 256, 0, stream>>>(hbuf, bb1, x, 1.0f, nullptr, iter_emb, BS_ * D_, D_ - 1);
  mem_read(hbuf, bb1, cc0b, henh);
  compute_block(henh, hcomp, bb3);
  mem_write_csa(hcomp, bb3, cache0, cc0b);

  // ================= iteration 1 (last: cache update dead, skipped) =================
  k_combine2<<<eg(BS_ * D_), 256, 0, stream>>>(hbuf, bb1, hcomp, 2.0f, x, iter_emb + D_, BS_ * D_, D_ - 1);
  mem_read(hbuf, bb1, ccwb, henh);
  compute_block(henh, out, nullptr);
}